// Round 13
// baseline (20547.218 us; speedup 1.0000x reference)
//
#include <hip/hip_runtime.h>
#include <stdint.h>

// ---------------- constants ----------------
#define T_STEPS 1000
#define SDIM    128
#define ADIM    32
#define HID     256
#define TDIM    16
#define KPX     40                     // padded K stride for x tile (32 used)
#define KPH     268                    // padded K stride for hidden tiles (256 used)
                                       // 268 ush = 134 dw ≡ 6 mod 32: A-row reads 2-way
                                       // (free), epi quad-writes conflict-free
#define W0P     20                     // padded row stride (dwords) for w0l in LDS

typedef __attribute__((ext_vector_type(8))) short short8;   // 8 bf16 (4 VGPRs)
typedef __attribute__((ext_vector_type(4))) float f32x4;    // MFMA accumulator
typedef __attribute__((ext_vector_type(4))) int   i32x4;

#define MFMA(A, B, C) __builtin_amdgcn_mfma_f32_16x16x32_bf16((A), (B), (C), 0, 0, 0)

// Barrier that drains LDS ops but leaves global loads (prefetches) in flight.
__device__ __forceinline__ void barrier_lgkm() {
  asm volatile("s_waitcnt lgkmcnt(0)" ::: "memory");
  __builtin_amdgcn_s_barrier();
  asm volatile("" ::: "memory");
}

// ---------------- bf16 helpers (RNE) ----------------
__device__ __forceinline__ unsigned short f2bf(float f) {
  uint32_t u = __float_as_uint(f);
  u = u + 0x7FFFu + ((u >> 16) & 1u);
  return (unsigned short)(u >> 16);
}
__device__ __forceinline__ float bf2f(unsigned short h) {
  return __uint_as_float(((uint32_t)h) << 16);
}

// ---------------- threefry2x32 (exact JAX semantics) ----------------
__device__ __forceinline__ uint32_t rotl32(uint32_t v, int d) {
  return (v << d) | (v >> (32 - d));
}
__device__ __forceinline__ void threefry2x32(uint32_t k0, uint32_t k1,
                                             uint32_t x0, uint32_t x1,
                                             uint32_t& o0, uint32_t& o1) {
  uint32_t ks0 = k0, ks1 = k1, ks2 = k0 ^ k1 ^ 0x1BD11BDAu;
  x0 += ks0; x1 += ks1;
#define TF_ROUND(r) { x0 += x1; x1 = rotl32(x1, (r)); x1 ^= x0; }
  TF_ROUND(13) TF_ROUND(15) TF_ROUND(26) TF_ROUND(6)
  x0 += ks1; x1 += ks2 + 1u;
  TF_ROUND(17) TF_ROUND(29) TF_ROUND(16) TF_ROUND(24)
  x0 += ks2; x1 += ks0 + 2u;
  TF_ROUND(13) TF_ROUND(15) TF_ROUND(26) TF_ROUND(6)
  x0 += ks0; x1 += ks1 + 3u;
  TF_ROUND(17) TF_ROUND(29) TF_ROUND(16) TF_ROUND(24)
  x0 += ks1; x1 += ks2 + 4u;
  TF_ROUND(13) TF_ROUND(15) TF_ROUND(26) TF_ROUND(6)
  x0 += ks2; x1 += ks0 + 5u;
#undef TF_ROUND
  o0 = x0; o1 = x1;
}
__device__ __forceinline__ uint32_t random_bits32_partitionable(uint32_t k0, uint32_t k1,
                                                               uint32_t j) {
  uint32_t o0, o1;
  threefry2x32(k0, k1, 0u, j, o0, o1);
  return o0 ^ o1;
}

// ---------------- XLA ErfInv (f32 Giles polynomial) ----------------
__device__ __forceinline__ float erfinv_f32(float x) {
  float w = -log1pf(-(x * x));
  float p;
  if (w < 5.0f) {
    w = w - 2.5f;
    p = 2.81022636e-08f;
    p = fmaf(p, w, 3.43273939e-07f);
    p = fmaf(p, w, -3.5233877e-06f);
    p = fmaf(p, w, -4.39150654e-06f);
    p = fmaf(p, w, 0.00021858087f);
    p = fmaf(p, w, -0.00125372503f);
    p = fmaf(p, w, -0.00417768164f);
    p = fmaf(p, w, 0.246640727f);
    p = fmaf(p, w, 1.50140941f);
  } else {
    w = sqrtf(w) - 3.0f;
    p = -0.000200214257f;
    p = fmaf(p, w, 0.000100950558f);
    p = fmaf(p, w, 0.00134934322f);
    p = fmaf(p, w, -0.00367342844f);
    p = fmaf(p, w, 0.00573950773f);
    p = fmaf(p, w, -0.0076224613f);
    p = fmaf(p, w, 0.00943887047f);
    p = fmaf(p, w, 1.00167406f);
    p = fmaf(p, w, 2.83297682f);
  }
  return p * x;
}
__device__ __forceinline__ float bits_to_normal(uint32_t bits) {
  float f = __uint_as_float((bits >> 9) | 0x3F800000u) - 1.0f;   // [0,1)
  float u = f * 2.0f + (-0.99999994f);
  u = fmaxf(-0.99999994f, u);
  return 1.41421356237309515f * erfinv_f32(u);   // sqrt(2) as f32
}

// mish(x) = x * t/(t+2), t = e^x (e^x + 2)
__device__ __forceinline__ float mish_f(float x) {
  float e = expf(fminf(x, 20.0f));
  float t = fmaf(e, e, 2.0f * e);
  return x * (t / (t + 2.0f));
}

// ---------------- precompute: tf_all[1000][16], coefs[5][1000], keys[1000][2] -----
__global__ __launch_bounds__(64)
void precompute_kernel(const float* __restrict__ w_t1, const float* __restrict__ b_t1,
                       const float* __restrict__ w_t2, const float* __restrict__ b_t2,
                       float* __restrict__ tf_all, float* __restrict__ coefs,
                       uint32_t* __restrict__ keys) {
  const int i = blockIdx.x;
  const int j = threadIdx.x;
  const float tv = (float)i;
  __shared__ float hid[32];
  const float CF = (float)(-1.3157629102823120);  // -log(10000)/7
  if (j < 32) {
    float acc = b_t1[j];
#pragma unroll
    for (int k = 0; k < 16; ++k) {
      int kf = (k < 8) ? k : (k - 8);
      float fr = expf((float)kf * CF);
      float ang = tv * fr;
      float te = (k < 8) ? sinf(ang) : cosf(ang);
      acc = fmaf(te, w_t1[k * 32 + j], acc);
    }
    hid[j] = mish_f(acc);
  }
  __syncthreads();
  if (j < 16) {
    float acc = b_t2[j];
#pragma unroll
    for (int k2 = 0; k2 < 32; ++k2) acc = fmaf(hid[k2], w_t2[k2 * 16 + j], acc);
    tf_all[i * TDIM + j] = acc;
  }
  if (j == 0) {
    double t = (double)(i + 1);
    double ac  = exp(-0.1 * t / 1000.0 - 4.95 * t * t / 1.0e6);
    double acp = (i == 0) ? 1.0
        : exp(-0.1 * (t - 1.0) / 1000.0 - 4.95 * (t - 1.0) * (t - 1.0) / 1.0e6);
    double alpha = exp(-0.1 / 1000.0 - 4.95 * (2.0 * t - 1.0) / 1.0e6);
    double beta = 1.0 - alpha;
    double sr   = sqrt(1.0 / ac);
    double srm1 = sqrt(1.0 / ac - 1.0);
    double c1 = beta * sqrt(acp) / (1.0 - ac);
    double c2 = (1.0 - acp) * sqrt(alpha) / (1.0 - ac);
    double pv = beta * (1.0 - acp) / (1.0 - ac);
    double lv = log(fmax(pv, 1.0e-20));
    coefs[0 * T_STEPS + i] = (float)sr;
    coefs[1 * T_STEPS + i] = (float)srm1;
    coefs[2 * T_STEPS + i] = (float)c1;
    coefs[3 * T_STEPS + i] = (float)c2;
    float lvf = (float)lv;
    coefs[4 * T_STEPS + i] = expf(0.5f * lvf);
    uint32_t o0, o1;
    threefry2x32(0u, 1u, 0u, (uint32_t)i, o0, o1);
    keys[2 * i]     = o0;
    keys[2 * i + 1] = o1;
  }
}

// -------- prep: MFMA B-fragment hi/lo layout + w0tf transpose ---------------------
__global__ __launch_bounds__(64)
void prep_frags(const float* __restrict__ w0, const float* __restrict__ w1,
                const float* __restrict__ w2, const float* __restrict__ wf,
                unsigned short* __restrict__ f0x, unsigned short* __restrict__ f0s,
                unsigned short* __restrict__ f1, unsigned short* __restrict__ f2,
                unsigned short* __restrict__ ff, float* __restrict__ w0tf) {
  const int bid = blockIdx.x;   // 0..355
  const int l = threadIdx.x;    // 0..63
  if (bid >= 352) {             // w0tf transpose
    int n = (bid - 352) * 64 + l;
#pragma unroll
    for (int c = 0; c < 16; ++c) w0tf[n * 16 + c] = w0[(32 + c) * HID + n];
    return;
  }
  const float* W; unsigned short* F; int NT, N, idx, rowoff, Kmax;
  if (bid < 16)       { W = w0; F = f0x; NT = 16; N = 256; idx = bid;       rowoff = 0;  Kmax = 32;  }
  else if (bid < 80)  { W = w0; F = f0s; NT = 16; N = 256; idx = bid - 16;  rowoff = 48; Kmax = 128; }
  else if (bid < 208) { W = w1; F = f1;  NT = 16; N = 256; idx = bid - 80;  rowoff = 0;  Kmax = 256; }
  else if (bid < 336) { W = w2; F = f2;  NT = 16; N = 256; idx = bid - 208; rowoff = 0;  Kmax = 256; }
  else                { W = wf; F = ff;  NT = 2;  N = 32;  idx = bid - 336; rowoff = 0;  Kmax = 256; }
  const int kt = idx / NT, nt = idx % NT;
  const int n = nt * 16 + (l & 15);
  const int kbase = kt * 32 + (l >> 4) * 8;
  unsigned short* dst = F + idx * 1024 + l * 8;
#pragma unroll
  for (int j = 0; j < 8; ++j) {
    int k = kbase + j;
    float v = (k < Kmax) ? W[(rowoff + k) * N + n] : 0.0f;
    unsigned short h = f2bf(v);
    dst[j]       = h;
    dst[512 + j] = f2bf(v - bf2f(h));
  }
}

// ---------------- persistent main kernel ------------------------------------------
// Grid 256 (1 block/CU), 1024 threads (16 waves), wave w owns nt-column w.
// LDS-resident: ff (32K), w0tf padded (20K), f2 kt0-1 (64K). F1 in AGPRs (pinned).
// Barriers B1..B4 drain lgkmcnt only -> global prefetches survive barriers.
// RNG distributed: threads 0-511 compute nzv into s_nz during L2 phase; LF+posterior
// fused on waves 14,15 reads s_nz. 4 barriers/iter. KPH=268 for bank-conflict-free
// A-reads and epi-writes.
__global__ __launch_bounds__(1024)
void diffusion_main(const float* __restrict__ state, const float* __restrict__ x_init,
                    const float* __restrict__ b0, const float* __restrict__ b1,
                    const float* __restrict__ b2, const float* __restrict__ bf,
                    const unsigned short* __restrict__ f0x, const unsigned short* __restrict__ f0s,
                    const unsigned short* __restrict__ f1, const unsigned short* __restrict__ f2,
                    const unsigned short* __restrict__ ff,
                    const float* __restrict__ tf_all, const float* __restrict__ w0tf,
                    const float* __restrict__ coefs,
                    const uint32_t* __restrict__ keys, float* __restrict__ out) {
  __shared__ __align__(16) unsigned short a0h[16][KPX], a0l[16][KPX];
  __shared__ __align__(16) unsigned short aAh[16][KPH], aAl[16][KPH];
  __shared__ __align__(16) unsigned short aBh[16][KPH], aBl[16][KPH];
  __shared__ __align__(16) unsigned short ffl[16 * 1024];   // ff resident (32 KB)
  __shared__ __align__(16) unsigned short f2l[32 * 1024];   // f2 kt0,1 resident (64 KB)
  __shared__ __align__(16) float w0l[HID * W0P];            // w0tf resident, padded (20 KB)
  __shared__ float s_x[16][ADIM];
  __shared__ float s_nz[16][33];                            // distributed RNG output

  const int tid = threadIdx.x;          // 0..1023
  const int base = blockIdx.x * 8;
  const int l = tid & 63;               // lane
  const int w = tid >> 6;               // wave 0..15
  const int lrow = l & 15;
  const int quad = l >> 4;              // 0..3
  const int nt = w;                     // one col-tile per wave

  // ---- stage x_init (16x32 = 512 elems; tid<512) ----
  if (tid < 512) {
    int r = tid >> 5, d = tid & 31;
    int grow = (r < 8) ? (base + r) : (2048 + base + r - 8);
    float v = x_init[grow * ADIM + d];
    s_x[r][d] = v;
    unsigned short h = f2bf(v);
    a0h[r][d] = h; a0l[r][d] = f2bf(v - bf2f(h));
  }
  // ---- stage state into aA cols 0..127 (one-time) ----
  for (int idx = tid; idx < 16 * SDIM; idx += 1024) {
    int r = idx >> 7, c = idx & 127;
    int grow = (r < 8) ? (base + r) : (2048 + base + r - 8);
    float v = state[grow * SDIM + c];
    unsigned short h = f2bf(v);
    aAh[r][c] = h; aAl[r][c] = f2bf(v - bf2f(h));
  }
  // ---- copy ff (32 KB), f2 kt0,1 (64 KB) into LDS once ----
  {
    const int4* src = reinterpret_cast<const int4*>(ff);
    int4* dst = reinterpret_cast<int4*>(ffl);
    dst[tid] = src[tid];
    dst[tid + 1024] = src[tid + 1024];
  }
  {
    const int4* src = reinterpret_cast<const int4*>(f2);
    int4* dst = reinterpret_cast<int4*>(f2l);
#pragma unroll
    for (int i = 0; i < 4; ++i) dst[tid + i * 1024] = src[tid + i * 1024];
  }
  // ---- copy w0tf into padded LDS rows (stride W0P dwords, bank-spread) ----
  for (int idx = tid; idx < HID * TDIM; idx += 1024) {
    int n = idx >> 4, c = idx & 15;
    w0l[n * W0P + c] = w0tf[idx];
  }

  const float b0v = b0[nt * 16 + lrow];
  const float b1v = b1[nt * 16 + lrow];
  const float b2v = b2[nt * 16 + lrow];
  const float bfv = (w >= 14) ? bf[(w - 14) * 16 + lrow] : 0.0f;
  __syncthreads();

  // ---- one-time: sacc = state-part of layer0 for this wave's nt ----
  f32x4 sacc = {0.f, 0.f, 0.f, 0.f};
  {
    const unsigned short* aH = &aAh[0][0] + lrow * KPH + quad * 8;
    const unsigned short* aL = &aAl[0][0] + lrow * KPH + quad * 8;
#pragma unroll
    for (int kt = 0; kt < 4; ++kt) {
      short8 ah = *reinterpret_cast<const short8*>(aH + kt * 32);
      short8 al = *reinterpret_cast<const short8*>(aL + kt * 32);
      const unsigned short* p = f0s + (kt * 16 + nt) * 1024 + l * 8;
      short8 bh = *reinterpret_cast<const short8*>(p);
      short8 bl = *reinterpret_cast<const short8*>(p + 512);
      sacc = MFMA(ah, bh, sacc);
      sacc = MFMA(al, bh, sacc);
      sacc = MFMA(ah, bl, sacc);
    }
  }

  // ---- persistent loop-invariant x fragments (kt=0 of layer0, this nt) ----
  short8 Xh, Xl;
  {
    const unsigned short* p = f0x + nt * 1024 + l * 8;
    Xh = *reinterpret_cast<const short8*>(p);
    Xl = *reinterpret_cast<const short8*>(p + 512);
  }

  // ---- F1 slice -> AGPRs (64 dwords), written once, read per iter ----
#define DECL_AG(k) int AH0_##k, AH1_##k, AH2_##k, AH3_##k, \
                       AL0_##k, AL1_##k, AL2_##k, AL3_##k;
  DECL_AG(0) DECL_AG(1) DECL_AG(2) DECL_AG(3)
  DECL_AG(4) DECL_AG(5) DECL_AG(6) DECL_AG(7)
#define LOAD_AG(k) { \
    i32x4 hv = *reinterpret_cast<const i32x4*>(f1 + ((k) * 16 + nt) * 1024 + l * 8); \
    i32x4 lv = *reinterpret_cast<const i32x4*>(f1 + ((k) * 16 + nt) * 1024 + 512 + l * 8); \
    asm volatile("v_accvgpr_write_b32 %0, %1" : "=a"(AH0_##k) : "v"(hv[0])); \
    asm volatile("v_accvgpr_write_b32 %0, %1" : "=a"(AH1_##k) : "v"(hv[1])); \
    asm volatile("v_accvgpr_write_b32 %0, %1" : "=a"(AH2_##k) : "v"(hv[2])); \
    asm volatile("v_accvgpr_write_b32 %0, %1" : "=a"(AH3_##k) : "v"(hv[3])); \
    asm volatile("v_accvgpr_write_b32 %0, %1" : "=a"(AL0_##k) : "v"(lv[0])); \
    asm volatile("v_accvgpr_write_b32 %0, %1" : "=a"(AL1_##k) : "v"(lv[1])); \
    asm volatile("v_accvgpr_write_b32 %0, %1" : "=a"(AL2_##k) : "v"(lv[2])); \
    asm volatile("v_accvgpr_write_b32 %0, %1" : "=a"(AL3_##k) : "v"(lv[3])); }
  LOAD_AG(0) LOAD_AG(1) LOAD_AG(2) LOAD_AG(3)
  LOAD_AG(4) LOAD_AG(5) LOAD_AG(6) LOAD_AG(7)

  // ---- per-lane tf-bias dot (16 f32 FMAs; weights from padded LDS) ----
  float bt;
  auto compute_bt = [&](int tt) {
    const float4* tfr = reinterpret_cast<const float4*>(tf_all + tt * TDIM);
    const float4* wA = reinterpret_cast<const float4*>(&w0l[(nt * 16 + lrow) * W0P]);
    float a = 0.0f;
#pragma unroll
    for (int q = 0; q < 4; ++q) {
      float4 tq = tfr[q];
      float4 wa = wA[q];
      a = fmaf(tq.x, wa.x, a);
      a = fmaf(tq.y, wa.y, a);
      a = fmaf(tq.z, wa.z, a);
      a = fmaf(tq.w, wa.w, a);
    }
    bt = a;
  };
  compute_bt(T_STEPS - 1);

  // epilogue: acc -> mish -> hi/lo LDS tile (single nt column)
  auto epi_store = [&](const f32x4& acc, float bA,
                       unsigned short* dH, unsigned short* dL) {
#pragma unroll
    for (int reg = 0; reg < 4; ++reg) {
      int orow = quad * 4 + reg;
      float v = mish_f(acc[reg] + bA);
      unsigned short h = f2bf(v);
      dH[orow * KPH + nt * 16 + lrow] = h;
      dL[orow * KPH + nt * 16 + lrow] = f2bf(v - bf2f(h));
    }
  };

  __syncthreads();  // B0 (full drain, once)

  for (int t = T_STEPS - 1; t >= 0; --t) {
    float sr  = coefs[0 * T_STEPS + t];
    float srm = coefs[1 * T_STEPS + t];
    float c1  = coefs[2 * T_STEPS + t];
    float c2  = coefs[3 * T_STEPS + t];
    float sig = (t != 0) ? coefs[4 * T_STEPS + t] : 0.0f;
    uint32_t k0 = keys[2 * t], k1 = keys[2 * t + 1];

    // ---- L0: x-part only (1 kt), acc starts from persistent state part ----
    {
      f32x4 acc = sacc;
      short8 ah = *reinterpret_cast<const short8*>(&a0h[0][0] + lrow * KPX + quad * 8);
      short8 al = *reinterpret_cast<const short8*>(&a0l[0][0] + lrow * KPX + quad * 8);
      acc = MFMA(ah, Xh, acc);
      acc = MFMA(al, Xh, acc);
      acc = MFMA(ah, Xl, acc);
      epi_store(acc, b0v + bt, &aAh[0][0], &aAl[0][0]);
    }
    barrier_lgkm();  // B1: aA ready (global prefetches stay in flight)

    // ---- L1: weights from AGPRs (zero memory traffic); prefetch F2 kt2 ----
    short8 P2h, P2l;
    {
      f32x4 acc = {0.f, 0.f, 0.f, 0.f};
      const unsigned short* aH = &aAh[0][0] + lrow * KPH + quad * 8;
      const unsigned short* aL = &aAl[0][0] + lrow * KPH + quad * 8;
#define L1_STEP(k) { \
      int h0, h1, h2, h3, lo0, lo1, lo2, lo3; \
      asm volatile("v_accvgpr_read_b32 %0, %1" : "=v"(h0)  : "a"(AH0_##k)); \
      asm volatile("v_accvgpr_read_b32 %0, %1" : "=v"(h1)  : "a"(AH1_##k)); \
      asm volatile("v_accvgpr_read_b32 %0, %1" : "=v"(h2)  : "a"(AH2_##k)); \
      asm volatile("v_accvgpr_read_b32 %0, %1" : "=v"(h3)  : "a"(AH3_##k)); \
      asm volatile("v_accvgpr_read_b32 %0, %1" : "=v"(lo0) : "a"(AL0_##k)); \
      asm volatile("v_accvgpr_read_b32 %0, %1" : "=v"(lo1) : "a"(AL1_##k)); \
      asm volatile("v_accvgpr_read_b32 %0, %1" : "=v"(lo2) : "a"(AL2_##k)); \
      asm volatile("v_accvgpr_read_b32 %0, %1" : "=v"(lo3) : "a"(AL3_##k)); \
      i32x4 hv = {h0, h1, h2, h3}; \
      i32x4 lv = {lo0, lo1, lo2, lo3}; \
      short8 bh = *reinterpret_cast<short8*>(&hv); \
      short8 bl = *reinterpret_cast<short8*>(&lv); \
      short8 ah = *reinterpret_cast<const short8*>(aH + (k) * 32); \
      short8 al = *reinterpret_cast<const short8*>(aL + (k) * 32); \
      acc = MFMA(ah, bh, acc); \
      acc = MFMA(al, bh, acc); \
      acc = MFMA(ah, bl, acc); }
      L1_STEP(0) L1_STEP(1) L1_STEP(2) L1_STEP(3)
      L1_STEP(4) L1_STEP(5) L1_STEP(6) L1_STEP(7)
#undef L1_STEP
      {
        const unsigned short* p = f2 + (2 * 16 + nt) * 1024 + l * 8;
        P2h = *reinterpret_cast<const short8*>(p);
        P2l = *reinterpret_cast<const short8*>(p + 512);
      }
      epi_store(acc, b1v, &aBh[0][0], &aBl[0][0]);
    }
    barrier_lgkm();  // B2: aB ready (P2 still in flight)

    // ---- distributed RNG: threads 0-511, one nzv each (hides in L2 stalls) ----
    if (tid < 512) {
      int d = tid & 31, r = tid >> 5;
      int grow = (r < 8) ? (base + r) : (2048 + base + r - 8);
      uint32_t jflat = (uint32_t)(grow * ADIM + d);
      s_nz[r][d] = bits_to_normal(random_bits32_partitionable(k0, k1, jflat));
    }

    // ---- L2: kt0,1 from LDS; kt2 from prefetch; kt3..7 streamed ----
    {
      f32x4 acc = {0.f, 0.f, 0.f, 0.f};
      const unsigned short* aH = &aBh[0][0] + lrow * KPH + quad * 8;
      const unsigned short* aL = &aBl[0][0] + lrow * KPH + quad * 8;
#pragma unroll
      for (int kt = 0; kt < 2; ++kt) {
        const unsigned short* p = &f2l[0] + (kt * 16 + nt) * 1024 + l * 8;
        short8 bh = *reinterpret_cast<const short8*>(p);
        short8 bl = *reinterpret_cast<const short8*>(p + 512);
        short8 ah = *reinterpret_cast<const short8*>(aH + kt * 32);
        short8 al = *reinterpret_cast<const short8*>(aL + kt * 32);
        acc = MFMA(ah, bh, acc);
        acc = MFMA(al, bh, acc);
        acc = MFMA(ah, bl, acc);
      }
      {  // kt = 2 from prefetch
        short8 ah = *reinterpret_cast<const short8*>(aH + 2 * 32);
        short8 al = *reinterpret_cast<const short8*>(aL + 2 * 32);
        acc = MFMA(ah, P2h, acc);
        acc = MFMA(al, P2h, acc);
        acc = MFMA(ah, P2l, acc);
      }
#pragma unroll
      for (int kt = 3; kt < 8; ++kt) {
        const unsigned short* p = f2 + (kt * 16 + nt) * 1024 + l * 8;
        short8 bh = *reinterpret_cast<const short8*>(p);
        short8 bl = *reinterpret_cast<const short8*>(p + 512);
        short8 ah = *reinterpret_cast<const short8*>(aH + kt * 32);
        short8 al = *reinterpret_cast<const short8*>(aL + kt * 32);
        acc = MFMA(ah, bh, acc);
        acc = MFMA(al, bh, acc);
        acc = MFMA(ah, bl, acc);
      }
      epi_store(acc, b2v, &aAh[0][0], &aAl[0][0]);
    }
    barrier_lgkm();  // B3: aA(L2 out) + s_nz ready

    // ---- LF + fused posterior on waves 14,15 (eps stays in registers) ----
    if (w >= 14) {
      f32x4 acc = {0.f, 0.f, 0.f, 0.f};
      const unsigned short* aH = &aAh[0][0] + lrow * KPH + quad * 8;
      const unsigned short* aL = &aAl[0][0] + lrow * KPH + quad * 8;
      const int wf2 = w - 14;
#pragma unroll
      for (int kt = 0; kt < 8; ++kt) {
        const unsigned short* p = &ffl[0] + (kt * 2 + wf2) * 1024 + l * 8;
        short8 bh = *reinterpret_cast<const short8*>(p);
        short8 bl = *reinterpret_cast<const short8*>(p + 512);
        short8 ah = *reinterpret_cast<const short8*>(aH + kt * 32);
        short8 al = *reinterpret_cast<const short8*>(aL + kt * 32);
        acc = MFMA(ah, bh, acc);
        acc = MFMA(al, bh, acc);
        acc = MFMA(ah, bl, acc);
      }
      const int d = wf2 * 16 + lrow;
#pragma unroll
      for (int reg = 0; reg < 4; ++reg) {
        int r = quad * 4 + reg;
        float eps = acc[reg] + bfv;
        float nzv = s_nz[r][d];
        float xv = s_x[r][d];
        float x0v = fminf(fmaxf(sr * xv - srm * eps, -1.0f), 1.0f);
        float xn = c1 * x0v + c2 * xv + sig * nzv;
        s_x[r][d] = xn;
        unsigned short h = f2bf(xn);
        a0h[r][d] = h; a0l[r][d] = f2bf(xn - bf2f(h));
      }
    }
    // next iteration's tf-bias (all waves; overlaps LF+posterior)
    compute_bt((t > 0) ? (t - 1) : 0);
    barrier_lgkm();  // B4: a0/s_x ready for next L0
  }

  // ---- output ----
  if (tid < 512) {
    int r = tid >> 5, d = tid & 31;
    int grow = (r < 8) ? (base + r) : (2048 + base + r - 8);
    out[grow * ADIM + d] = fminf(fmaxf(s_x[r][d], -1.0f), 1.0f);
  }
}

// ---------------- launcher ----------------
extern "C" void kernel_launch(void* const* d_in, const int* in_sizes, int n_in,
                              void* d_out, int out_size, void* d_ws, size_t ws_size,
                              hipStream_t stream) {
  const float* state = (const float*)d_in[0];
  const float* x_init = (const float*)d_in[1];
  const float* w_t1 = (const float*)d_in[2];
  const float* b_t1 = (const float*)d_in[3];
  const float* w_t2 = (const float*)d_in[4];
  const float* b_t2 = (const float*)d_in[5];
  const float* w0 = (const float*)d_in[6];
  const float* b0 = (const float*)d_in[7];
  const float* w1 = (const float*)d_in[8];
  const float* b1 = (const float*)d_in[9];
  const float* w2 = (const float*)d_in[10];
  const float* b2 = (const float*)d_in[11];
  const float* wf = (const float*)d_in[12];
  const float* bf = (const float*)d_in[13];
  float* out = (float*)d_out;

  // ws layout (f32 units unless noted), total ~829 KB:
  //   tf_all[16000] | w0tf[4096] | coefs[5000] | keys[2000] u32
  //   | f0x[16K ush] | f0s[64K] | f1[128K] | f2[128K] | ff[16K]
  float* tf_all = (float*)d_ws;
  float* w0tf = tf_all + T_STEPS * TDIM;
  float* coefs = w0tf + HID * TDIM;
  uint32_t* keys = (uint32_t*)(coefs + 5 * T_STEPS);
  unsigned short* f0x = (unsigned short*)(keys + 2 * T_STEPS);
  unsigned short* f0s = f0x + 16 * 1024;
  unsigned short* f1 = f0s + 64 * 1024;
  unsigned short* f2 = f1 + 128 * 1024;
  unsigned short* ff = f2 + 128 * 1024;

  precompute_kernel<<<T_STEPS, 64, 0, stream>>>(w_t1, b_t1, w_t2, b_t2,
                                                tf_all, coefs, keys);
  prep_frags<<<356, 64, 0, stream>>>(w0, w1, w2, wf, f0x, f0s, f1, f2, ff, w0tf);
  diffusion_main<<<256, 1024, 0, stream>>>(state, x_init, b0, b1, b2, bf,
                                           f0x, f0s, f1, f2, ff,
                                           tf_all, w0tf, coefs, keys, out);
}

// Round 14
// 9540.518 us; speedup vs baseline: 2.1537x; 2.1537x over previous
//
#include <hip/hip_runtime.h>
#include <stdint.h>

// ---------------- constants ----------------
#define T_STEPS 1000
#define SDIM    128
#define ADIM    32
#define HID     256
#define TDIM    16
#define KPX     40                     // padded K stride for x tile (32 used)
#define KPH     264                    // padded K stride for hidden tiles (256 used)
                                       // NOTE: must stay ≡ 0 mod 8 ushorts (16B) so
                                       // ds_read_b128 alignment holds (KPH=268 broke
                                       // this: b128 reads split, 2x slowdown, r13)
#define W0P     20                     // padded row stride (dwords) for w0l in LDS

typedef __attribute__((ext_vector_type(8))) short short8;   // 8 bf16 (4 VGPRs)
typedef __attribute__((ext_vector_type(4))) float f32x4;    // MFMA accumulator
typedef __attribute__((ext_vector_type(4))) int   i32x4;

#define MFMA(A, B, C) __builtin_amdgcn_mfma_f32_16x16x32_bf16((A), (B), (C), 0, 0, 0)

// Barrier that drains LDS ops but leaves global loads (prefetches) in flight.
__device__ __forceinline__ void barrier_lgkm() {
  asm volatile("s_waitcnt lgkmcnt(0)" ::: "memory");
  __builtin_amdgcn_s_barrier();
  asm volatile("" ::: "memory");
}

// ---------------- bf16 helpers (RNE) ----------------
__device__ __forceinline__ unsigned short f2bf(float f) {
  uint32_t u = __float_as_uint(f);
  u = u + 0x7FFFu + ((u >> 16) & 1u);
  return (unsigned short)(u >> 16);
}
__device__ __forceinline__ float bf2f(unsigned short h) {
  return __uint_as_float(((uint32_t)h) << 16);
}

// ---------------- threefry2x32 (exact JAX semantics) ----------------
__device__ __forceinline__ uint32_t rotl32(uint32_t v, int d) {
  return (v << d) | (v >> (32 - d));
}
__device__ __forceinline__ void threefry2x32(uint32_t k0, uint32_t k1,
                                             uint32_t x0, uint32_t x1,
                                             uint32_t& o0, uint32_t& o1) {
  uint32_t ks0 = k0, ks1 = k1, ks2 = k0 ^ k1 ^ 0x1BD11BDAu;
  x0 += ks0; x1 += ks1;
#define TF_ROUND(r) { x0 += x1; x1 = rotl32(x1, (r)); x1 ^= x0; }
  TF_ROUND(13) TF_ROUND(15) TF_ROUND(26) TF_ROUND(6)
  x0 += ks1; x1 += ks2 + 1u;
  TF_ROUND(17) TF_ROUND(29) TF_ROUND(16) TF_ROUND(24)
  x0 += ks2; x1 += ks0 + 2u;
  TF_ROUND(13) TF_ROUND(15) TF_ROUND(26) TF_ROUND(6)
  x0 += ks0; x1 += ks1 + 3u;
  TF_ROUND(17) TF_ROUND(29) TF_ROUND(16) TF_ROUND(24)
  x0 += ks1; x1 += ks2 + 4u;
  TF_ROUND(13) TF_ROUND(15) TF_ROUND(26) TF_ROUND(6)
  x0 += ks2; x1 += ks0 + 5u;
#undef TF_ROUND
  o0 = x0; o1 = x1;
}
__device__ __forceinline__ uint32_t random_bits32_partitionable(uint32_t k0, uint32_t k1,
                                                               uint32_t j) {
  uint32_t o0, o1;
  threefry2x32(k0, k1, 0u, j, o0, o1);
  return o0 ^ o1;
}

// ---------------- XLA ErfInv (f32 Giles polynomial) ----------------
__device__ __forceinline__ float erfinv_f32(float x) {
  float w = -log1pf(-(x * x));
  float p;
  if (w < 5.0f) {
    w = w - 2.5f;
    p = 2.81022636e-08f;
    p = fmaf(p, w, 3.43273939e-07f);
    p = fmaf(p, w, -3.5233877e-06f);
    p = fmaf(p, w, -4.39150654e-06f);
    p = fmaf(p, w, 0.00021858087f);
    p = fmaf(p, w, -0.00125372503f);
    p = fmaf(p, w, -0.00417768164f);
    p = fmaf(p, w, 0.246640727f);
    p = fmaf(p, w, 1.50140941f);
  } else {
    w = sqrtf(w) - 3.0f;
    p = -0.000200214257f;
    p = fmaf(p, w, 0.000100950558f);
    p = fmaf(p, w, 0.00134934322f);
    p = fmaf(p, w, -0.00367342844f);
    p = fmaf(p, w, 0.00573950773f);
    p = fmaf(p, w, -0.0076224613f);
    p = fmaf(p, w, 0.00943887047f);
    p = fmaf(p, w, 1.00167406f);
    p = fmaf(p, w, 2.83297682f);
  }
  return p * x;
}
__device__ __forceinline__ float bits_to_normal(uint32_t bits) {
  float f = __uint_as_float((bits >> 9) | 0x3F800000u) - 1.0f;   // [0,1)
  float u = f * 2.0f + (-0.99999994f);
  u = fmaxf(-0.99999994f, u);
  return 1.41421356237309515f * erfinv_f32(u);   // sqrt(2) as f32
}

// mish(x) = x * t/(t+2), t = e^x (e^x + 2)
__device__ __forceinline__ float mish_f(float x) {
  float e = expf(fminf(x, 20.0f));
  float t = fmaf(e, e, 2.0f * e);
  return x * (t / (t + 2.0f));
}

// ---------------- precompute: tf_all[1000][16], coefs[5][1000], keys[1000][2] -----
__global__ __launch_bounds__(64)
void precompute_kernel(const float* __restrict__ w_t1, const float* __restrict__ b_t1,
                       const float* __restrict__ w_t2, const float* __restrict__ b_t2,
                       float* __restrict__ tf_all, float* __restrict__ coefs,
                       uint32_t* __restrict__ keys) {
  const int i = blockIdx.x;
  const int j = threadIdx.x;
  const float tv = (float)i;
  __shared__ float hid[32];
  const float CF = (float)(-1.3157629102823120);  // -log(10000)/7
  if (j < 32) {
    float acc = b_t1[j];
#pragma unroll
    for (int k = 0; k < 16; ++k) {
      int kf = (k < 8) ? k : (k - 8);
      float fr = expf((float)kf * CF);
      float ang = tv * fr;
      float te = (k < 8) ? sinf(ang) : cosf(ang);
      acc = fmaf(te, w_t1[k * 32 + j], acc);
    }
    hid[j] = mish_f(acc);
  }
  __syncthreads();
  if (j < 16) {
    float acc = b_t2[j];
#pragma unroll
    for (int k2 = 0; k2 < 32; ++k2) acc = fmaf(hid[k2], w_t2[k2 * 16 + j], acc);
    tf_all[i * TDIM + j] = acc;
  }
  if (j == 0) {
    double t = (double)(i + 1);
    double ac  = exp(-0.1 * t / 1000.0 - 4.95 * t * t / 1.0e6);
    double acp = (i == 0) ? 1.0
        : exp(-0.1 * (t - 1.0) / 1000.0 - 4.95 * (t - 1.0) * (t - 1.0) / 1.0e6);
    double alpha = exp(-0.1 / 1000.0 - 4.95 * (2.0 * t - 1.0) / 1.0e6);
    double beta = 1.0 - alpha;
    double sr   = sqrt(1.0 / ac);
    double srm1 = sqrt(1.0 / ac - 1.0);
    double c1 = beta * sqrt(acp) / (1.0 - ac);
    double c2 = (1.0 - acp) * sqrt(alpha) / (1.0 - ac);
    double pv = beta * (1.0 - acp) / (1.0 - ac);
    double lv = log(fmax(pv, 1.0e-20));
    coefs[0 * T_STEPS + i] = (float)sr;
    coefs[1 * T_STEPS + i] = (float)srm1;
    coefs[2 * T_STEPS + i] = (float)c1;
    coefs[3 * T_STEPS + i] = (float)c2;
    float lvf = (float)lv;
    coefs[4 * T_STEPS + i] = expf(0.5f * lvf);
    uint32_t o0, o1;
    threefry2x32(0u, 1u, 0u, (uint32_t)i, o0, o1);
    keys[2 * i]     = o0;
    keys[2 * i + 1] = o1;
  }
}

// -------- prep: MFMA B-fragment hi/lo layout + w0tf transpose ---------------------
__global__ __launch_bounds__(64)
void prep_frags(const float* __restrict__ w0, const float* __restrict__ w1,
                const float* __restrict__ w2, const float* __restrict__ wf,
                unsigned short* __restrict__ f0x, unsigned short* __restrict__ f0s,
                unsigned short* __restrict__ f1, unsigned short* __restrict__ f2,
                unsigned short* __restrict__ ff, float* __restrict__ w0tf) {
  const int bid = blockIdx.x;   // 0..355
  const int l = threadIdx.x;    // 0..63
  if (bid >= 352) {             // w0tf transpose
    int n = (bid - 352) * 64 + l;
#pragma unroll
    for (int c = 0; c < 16; ++c) w0tf[n * 16 + c] = w0[(32 + c) * HID + n];
    return;
  }
  const float* W; unsigned short* F; int NT, N, idx, rowoff, Kmax;
  if (bid < 16)       { W = w0; F = f0x; NT = 16; N = 256; idx = bid;       rowoff = 0;  Kmax = 32;  }
  else if (bid < 80)  { W = w0; F = f0s; NT = 16; N = 256; idx = bid - 16;  rowoff = 48; Kmax = 128; }
  else if (bid < 208) { W = w1; F = f1;  NT = 16; N = 256; idx = bid - 80;  rowoff = 0;  Kmax = 256; }
  else if (bid < 336) { W = w2; F = f2;  NT = 16; N = 256; idx = bid - 208; rowoff = 0;  Kmax = 256; }
  else                { W = wf; F = ff;  NT = 2;  N = 32;  idx = bid - 336; rowoff = 0;  Kmax = 256; }
  const int kt = idx / NT, nt = idx % NT;
  const int n = nt * 16 + (l & 15);
  const int kbase = kt * 32 + (l >> 4) * 8;
  unsigned short* dst = F + idx * 1024 + l * 8;
#pragma unroll
  for (int j = 0; j < 8; ++j) {
    int k = kbase + j;
    float v = (k < Kmax) ? W[(rowoff + k) * N + n] : 0.0f;
    unsigned short h = f2bf(v);
    dst[j]       = h;
    dst[512 + j] = f2bf(v - bf2f(h));
  }
}

// ---------------- persistent main kernel ------------------------------------------
// Grid 256 (1 block/CU), 1024 threads (16 waves), wave w owns nt-column w.
// LDS-resident: ff (32K), w0tf padded (20K), f2 kt0-1 (64K). F1 in AGPRs (pinned).
// Barriers B1..B4 drain lgkmcnt only -> global prefetches survive barriers.
// RNG distributed: threads 0-511 compute nzv into s_nz during L2 phase; LF+posterior
// fused on waves 14,15 reads s_nz. 4 barriers/iter.
__global__ __launch_bounds__(1024)
void diffusion_main(const float* __restrict__ state, const float* __restrict__ x_init,
                    const float* __restrict__ b0, const float* __restrict__ b1,
                    const float* __restrict__ b2, const float* __restrict__ bf,
                    const unsigned short* __restrict__ f0x, const unsigned short* __restrict__ f0s,
                    const unsigned short* __restrict__ f1, const unsigned short* __restrict__ f2,
                    const unsigned short* __restrict__ ff,
                    const float* __restrict__ tf_all, const float* __restrict__ w0tf,
                    const float* __restrict__ coefs,
                    const uint32_t* __restrict__ keys, float* __restrict__ out) {
  __shared__ __align__(16) unsigned short a0h[16][KPX], a0l[16][KPX];
  __shared__ __align__(16) unsigned short aAh[16][KPH], aAl[16][KPH];
  __shared__ __align__(16) unsigned short aBh[16][KPH], aBl[16][KPH];
  __shared__ __align__(16) unsigned short ffl[16 * 1024];   // ff resident (32 KB)
  __shared__ __align__(16) unsigned short f2l[32 * 1024];   // f2 kt0,1 resident (64 KB)
  __shared__ __align__(16) float w0l[HID * W0P];            // w0tf resident, padded (20 KB)
  __shared__ float s_x[16][ADIM];
  __shared__ float s_nz[16][33];                            // distributed RNG output

  const int tid = threadIdx.x;          // 0..1023
  const int base = blockIdx.x * 8;
  const int l = tid & 63;               // lane
  const int w = tid >> 6;               // wave 0..15
  const int lrow = l & 15;
  const int quad = l >> 4;              // 0..3
  const int nt = w;                     // one col-tile per wave

  // ---- stage x_init (16x32 = 512 elems; tid<512) ----
  if (tid < 512) {
    int r = tid >> 5, d = tid & 31;
    int grow = (r < 8) ? (base + r) : (2048 + base + r - 8);
    float v = x_init[grow * ADIM + d];
    s_x[r][d] = v;
    unsigned short h = f2bf(v);
    a0h[r][d] = h; a0l[r][d] = f2bf(v - bf2f(h));
  }
  // ---- stage state into aA cols 0..127 (one-time) ----
  for (int idx = tid; idx < 16 * SDIM; idx += 1024) {
    int r = idx >> 7, c = idx & 127;
    int grow = (r < 8) ? (base + r) : (2048 + base + r - 8);
    float v = state[grow * SDIM + c];
    unsigned short h = f2bf(v);
    aAh[r][c] = h; aAl[r][c] = f2bf(v - bf2f(h));
  }
  // ---- copy ff (32 KB), f2 kt0,1 (64 KB) into LDS once ----
  {
    const int4* src = reinterpret_cast<const int4*>(ff);
    int4* dst = reinterpret_cast<int4*>(ffl);
    dst[tid] = src[tid];
    dst[tid + 1024] = src[tid + 1024];
  }
  {
    const int4* src = reinterpret_cast<const int4*>(f2);
    int4* dst = reinterpret_cast<int4*>(f2l);
#pragma unroll
    for (int i = 0; i < 4; ++i) dst[tid + i * 1024] = src[tid + i * 1024];
  }
  // ---- copy w0tf into padded LDS rows (stride W0P dwords, bank-spread) ----
  for (int idx = tid; idx < HID * TDIM; idx += 1024) {
    int n = idx >> 4, c = idx & 15;
    w0l[n * W0P + c] = w0tf[idx];
  }

  const float b0v = b0[nt * 16 + lrow];
  const float b1v = b1[nt * 16 + lrow];
  const float b2v = b2[nt * 16 + lrow];
  const float bfv = (w >= 14) ? bf[(w - 14) * 16 + lrow] : 0.0f;
  __syncthreads();

  // ---- one-time: sacc = state-part of layer0 for this wave's nt ----
  f32x4 sacc = {0.f, 0.f, 0.f, 0.f};
  {
    const unsigned short* aH = &aAh[0][0] + lrow * KPH + quad * 8;
    const unsigned short* aL = &aAl[0][0] + lrow * KPH + quad * 8;
#pragma unroll
    for (int kt = 0; kt < 4; ++kt) {
      short8 ah = *reinterpret_cast<const short8*>(aH + kt * 32);
      short8 al = *reinterpret_cast<const short8*>(aL + kt * 32);
      const unsigned short* p = f0s + (kt * 16 + nt) * 1024 + l * 8;
      short8 bh = *reinterpret_cast<const short8*>(p);
      short8 bl = *reinterpret_cast<const short8*>(p + 512);
      sacc = MFMA(ah, bh, sacc);
      sacc = MFMA(al, bh, sacc);
      sacc = MFMA(ah, bl, sacc);
    }
  }

  // ---- persistent loop-invariant x fragments (kt=0 of layer0, this nt) ----
  short8 Xh, Xl;
  {
    const unsigned short* p = f0x + nt * 1024 + l * 8;
    Xh = *reinterpret_cast<const short8*>(p);
    Xl = *reinterpret_cast<const short8*>(p + 512);
  }

  // ---- F1 slice -> AGPRs (64 dwords), written once, read per iter ----
#define DECL_AG(k) int AH0_##k, AH1_##k, AH2_##k, AH3_##k, \
                       AL0_##k, AL1_##k, AL2_##k, AL3_##k;
  DECL_AG(0) DECL_AG(1) DECL_AG(2) DECL_AG(3)
  DECL_AG(4) DECL_AG(5) DECL_AG(6) DECL_AG(7)
#define LOAD_AG(k) { \
    i32x4 hv = *reinterpret_cast<const i32x4*>(f1 + ((k) * 16 + nt) * 1024 + l * 8); \
    i32x4 lv = *reinterpret_cast<const i32x4*>(f1 + ((k) * 16 + nt) * 1024 + 512 + l * 8); \
    asm volatile("v_accvgpr_write_b32 %0, %1" : "=a"(AH0_##k) : "v"(hv[0])); \
    asm volatile("v_accvgpr_write_b32 %0, %1" : "=a"(AH1_##k) : "v"(hv[1])); \
    asm volatile("v_accvgpr_write_b32 %0, %1" : "=a"(AH2_##k) : "v"(hv[2])); \
    asm volatile("v_accvgpr_write_b32 %0, %1" : "=a"(AH3_##k) : "v"(hv[3])); \
    asm volatile("v_accvgpr_write_b32 %0, %1" : "=a"(AL0_##k) : "v"(lv[0])); \
    asm volatile("v_accvgpr_write_b32 %0, %1" : "=a"(AL1_##k) : "v"(lv[1])); \
    asm volatile("v_accvgpr_write_b32 %0, %1" : "=a"(AL2_##k) : "v"(lv[2])); \
    asm volatile("v_accvgpr_write_b32 %0, %1" : "=a"(AL3_##k) : "v"(lv[3])); }
  LOAD_AG(0) LOAD_AG(1) LOAD_AG(2) LOAD_AG(3)
  LOAD_AG(4) LOAD_AG(5) LOAD_AG(6) LOAD_AG(7)

  // ---- per-lane tf-bias dot (16 f32 FMAs; weights from padded LDS) ----
  float bt;
  auto compute_bt = [&](int tt) {
    const float4* tfr = reinterpret_cast<const float4*>(tf_all + tt * TDIM);
    const float4* wA = reinterpret_cast<const float4*>(&w0l[(nt * 16 + lrow) * W0P]);
    float a = 0.0f;
#pragma unroll
    for (int q = 0; q < 4; ++q) {
      float4 tq = tfr[q];
      float4 wa = wA[q];
      a = fmaf(tq.x, wa.x, a);
      a = fmaf(tq.y, wa.y, a);
      a = fmaf(tq.z, wa.z, a);
      a = fmaf(tq.w, wa.w, a);
    }
    bt = a;
  };
  compute_bt(T_STEPS - 1);

  // epilogue: acc -> mish -> hi/lo LDS tile (single nt column)
  auto epi_store = [&](const f32x4& acc, float bA,
                       unsigned short* dH, unsigned short* dL) {
#pragma unroll
    for (int reg = 0; reg < 4; ++reg) {
      int orow = quad * 4 + reg;
      float v = mish_f(acc[reg] + bA);
      unsigned short h = f2bf(v);
      dH[orow * KPH + nt * 16 + lrow] = h;
      dL[orow * KPH + nt * 16 + lrow] = f2bf(v - bf2f(h));
    }
  };

  __syncthreads();  // B0 (full drain, once)

  for (int t = T_STEPS - 1; t >= 0; --t) {
    float sr  = coefs[0 * T_STEPS + t];
    float srm = coefs[1 * T_STEPS + t];
    float c1  = coefs[2 * T_STEPS + t];
    float c2  = coefs[3 * T_STEPS + t];
    float sig = (t != 0) ? coefs[4 * T_STEPS + t] : 0.0f;
    uint32_t k0 = keys[2 * t], k1 = keys[2 * t + 1];

    // ---- L0: x-part only (1 kt), acc starts from persistent state part ----
    {
      f32x4 acc = sacc;
      short8 ah = *reinterpret_cast<const short8*>(&a0h[0][0] + lrow * KPX + quad * 8);
      short8 al = *reinterpret_cast<const short8*>(&a0l[0][0] + lrow * KPX + quad * 8);
      acc = MFMA(ah, Xh, acc);
      acc = MFMA(al, Xh, acc);
      acc = MFMA(ah, Xl, acc);
      epi_store(acc, b0v + bt, &aAh[0][0], &aAl[0][0]);
    }
    barrier_lgkm();  // B1: aA ready (global prefetches stay in flight)

    // ---- L1: weights from AGPRs (zero memory traffic); prefetch F2 kt2 ----
    short8 P2h, P2l;
    {
      f32x4 acc = {0.f, 0.f, 0.f, 0.f};
      const unsigned short* aH = &aAh[0][0] + lrow * KPH + quad * 8;
      const unsigned short* aL = &aAl[0][0] + lrow * KPH + quad * 8;
#define L1_STEP(k) { \
      int h0, h1, h2, h3, lo0, lo1, lo2, lo3; \
      asm volatile("v_accvgpr_read_b32 %0, %1" : "=v"(h0)  : "a"(AH0_##k)); \
      asm volatile("v_accvgpr_read_b32 %0, %1" : "=v"(h1)  : "a"(AH1_##k)); \
      asm volatile("v_accvgpr_read_b32 %0, %1" : "=v"(h2)  : "a"(AH2_##k)); \
      asm volatile("v_accvgpr_read_b32 %0, %1" : "=v"(h3)  : "a"(AH3_##k)); \
      asm volatile("v_accvgpr_read_b32 %0, %1" : "=v"(lo0) : "a"(AL0_##k)); \
      asm volatile("v_accvgpr_read_b32 %0, %1" : "=v"(lo1) : "a"(AL1_##k)); \
      asm volatile("v_accvgpr_read_b32 %0, %1" : "=v"(lo2) : "a"(AL2_##k)); \
      asm volatile("v_accvgpr_read_b32 %0, %1" : "=v"(lo3) : "a"(AL3_##k)); \
      i32x4 hv = {h0, h1, h2, h3}; \
      i32x4 lv = {lo0, lo1, lo2, lo3}; \
      short8 bh = *reinterpret_cast<short8*>(&hv); \
      short8 bl = *reinterpret_cast<short8*>(&lv); \
      short8 ah = *reinterpret_cast<const short8*>(aH + (k) * 32); \
      short8 al = *reinterpret_cast<const short8*>(aL + (k) * 32); \
      acc = MFMA(ah, bh, acc); \
      acc = MFMA(al, bh, acc); \
      acc = MFMA(ah, bl, acc); }
      L1_STEP(0) L1_STEP(1) L1_STEP(2) L1_STEP(3)
      L1_STEP(4) L1_STEP(5) L1_STEP(6) L1_STEP(7)
#undef L1_STEP
      {
        const unsigned short* p = f2 + (2 * 16 + nt) * 1024 + l * 8;
        P2h = *reinterpret_cast<const short8*>(p);
        P2l = *reinterpret_cast<const short8*>(p + 512);
      }
      epi_store(acc, b1v, &aBh[0][0], &aBl[0][0]);
    }
    barrier_lgkm();  // B2: aB ready (P2 still in flight)

    // ---- distributed RNG: threads 0-511, one nzv each (hides in L2 stalls) ----
    if (tid < 512) {
      int d = tid & 31, r = tid >> 5;
      int grow = (r < 8) ? (base + r) : (2048 + base + r - 8);
      uint32_t jflat = (uint32_t)(grow * ADIM + d);
      s_nz[r][d] = bits_to_normal(random_bits32_partitionable(k0, k1, jflat));
    }

    // ---- L2: kt0,1 from LDS; kt2 from prefetch; kt3..7 streamed ----
    {
      f32x4 acc = {0.f, 0.f, 0.f, 0.f};
      const unsigned short* aH = &aBh[0][0] + lrow * KPH + quad * 8;
      const unsigned short* aL = &aBl[0][0] + lrow * KPH + quad * 8;
#pragma unroll
      for (int kt = 0; kt < 2; ++kt) {
        const unsigned short* p = &f2l[0] + (kt * 16 + nt) * 1024 + l * 8;
        short8 bh = *reinterpret_cast<const short8*>(p);
        short8 bl = *reinterpret_cast<const short8*>(p + 512);
        short8 ah = *reinterpret_cast<const short8*>(aH + kt * 32);
        short8 al = *reinterpret_cast<const short8*>(aL + kt * 32);
        acc = MFMA(ah, bh, acc);
        acc = MFMA(al, bh, acc);
        acc = MFMA(ah, bl, acc);
      }
      {  // kt = 2 from prefetch
        short8 ah = *reinterpret_cast<const short8*>(aH + 2 * 32);
        short8 al = *reinterpret_cast<const short8*>(aL + 2 * 32);
        acc = MFMA(ah, P2h, acc);
        acc = MFMA(al, P2h, acc);
        acc = MFMA(ah, P2l, acc);
      }
#pragma unroll
      for (int kt = 3; kt < 8; ++kt) {
        const unsigned short* p = f2 + (kt * 16 + nt) * 1024 + l * 8;
        short8 bh = *reinterpret_cast<const short8*>(p);
        short8 bl = *reinterpret_cast<const short8*>(p + 512);
        short8 ah = *reinterpret_cast<const short8*>(aH + kt * 32);
        short8 al = *reinterpret_cast<const short8*>(aL + kt * 32);
        acc = MFMA(ah, bh, acc);
        acc = MFMA(al, bh, acc);
        acc = MFMA(ah, bl, acc);
      }
      epi_store(acc, b2v, &aAh[0][0], &aAl[0][0]);
    }
    barrier_lgkm();  // B3: aA(L2 out) + s_nz ready

    // ---- LF + fused posterior on waves 14,15 (eps stays in registers) ----
    if (w >= 14) {
      f32x4 acc = {0.f, 0.f, 0.f, 0.f};
      const unsigned short* aH = &aAh[0][0] + lrow * KPH + quad * 8;
      const unsigned short* aL = &aAl[0][0] + lrow * KPH + quad * 8;
      const int wf2 = w - 14;
#pragma unroll
      for (int kt = 0; kt < 8; ++kt) {
        const unsigned short* p = &ffl[0] + (kt * 2 + wf2) * 1024 + l * 8;
        short8 bh = *reinterpret_cast<const short8*>(p);
        short8 bl = *reinterpret_cast<const short8*>(p + 512);
        short8 ah = *reinterpret_cast<const short8*>(aH + kt * 32);
        short8 al = *reinterpret_cast<const short8*>(aL + kt * 32);
        acc = MFMA(ah, bh, acc);
        acc = MFMA(al, bh, acc);
        acc = MFMA(ah, bl, acc);
      }
      const int d = wf2 * 16 + lrow;
#pragma unroll
      for (int reg = 0; reg < 4; ++reg) {
        int r = quad * 4 + reg;
        float eps = acc[reg] + bfv;
        float nzv = s_nz[r][d];
        float xv = s_x[r][d];
        float x0v = fminf(fmaxf(sr * xv - srm * eps, -1.0f), 1.0f);
        float xn = c1 * x0v + c2 * xv + sig * nzv;
        s_x[r][d] = xn;
        unsigned short h = f2bf(xn);
        a0h[r][d] = h; a0l[r][d] = f2bf(xn - bf2f(h));
      }
    }
    // next iteration's tf-bias (all waves; overlaps LF+posterior)
    compute_bt((t > 0) ? (t - 1) : 0);
    barrier_lgkm();  // B4: a0/s_x ready for next L0
  }

  // ---- output ----
  if (tid < 512) {
    int r = tid >> 5, d = tid & 31;
    int grow = (r < 8) ? (base + r) : (2048 + base + r - 8);
    out[grow * ADIM + d] = fminf(fmaxf(s_x[r][d], -1.0f), 1.0f);
  }
}

// ---------------- launcher ----------------
extern "C" void kernel_launch(void* const* d_in, const int* in_sizes, int n_in,
                              void* d_out, int out_size, void* d_ws, size_t ws_size,
                              hipStream_t stream) {
  const float* state = (const float*)d_in[0];
  const float* x_init = (const float*)d_in[1];
  const float* w_t1 = (const float*)d_in[2];
  const float* b_t1 = (const float*)d_in[3];
  const float* w_t2 = (const float*)d_in[4];
  const float* b_t2 = (const float*)d_in[5];
  const float* w0 = (const float*)d_in[6];
  const float* b0 = (const float*)d_in[7];
  const float* w1 = (const float*)d_in[8];
  const float* b1 = (const float*)d_in[9];
  const float* w2 = (const float*)d_in[10];
  const float* b2 = (const float*)d_in[11];
  const float* wf = (const float*)d_in[12];
  const float* bf = (const float*)d_in[13];
  float* out = (float*)d_out;

  // ws layout (f32 units unless noted), total ~829 KB:
  //   tf_all[16000] | w0tf[4096] | coefs[5000] | keys[2000] u32
  //   | f0x[16K ush] | f0s[64K] | f1[128K] | f2[128K] | ff[16K]
  float* tf_all = (float*)d_ws;
  float* w0tf = tf_all + T_STEPS * TDIM;
  float* coefs = w0tf + HID * TDIM;
  uint32_t* keys = (uint32_t*)(coefs + 5 * T_STEPS);
  unsigned short* f0x = (unsigned short*)(keys + 2 * T_STEPS);
  unsigned short* f0s = f0x + 16 * 1024;
  unsigned short* f1 = f0s + 64 * 1024;
  unsigned short* f2 = f1 + 128 * 1024;
  unsigned short* ff = f2 + 128 * 1024;

  precompute_kernel<<<T_STEPS, 64, 0, stream>>>(w_t1, b_t1, w_t2, b_t2,
                                                tf_all, coefs, keys);
  prep_frags<<<356, 64, 0, stream>>>(w0, w1, w2, wf, f0x, f0s, f1, f2, ff, w0tf);
  diffusion_main<<<256, 1024, 0, stream>>>(state, x_init, b0, b1, b2, bf,
                                           f0x, f0s, f1, f2, ff,
                                           tf_all, w0tf, coefs, keys, out);
}

// Round 15
// 6995.010 us; speedup vs baseline: 2.9374x; 1.3639x over previous
//
#include <hip/hip_runtime.h>
#include <stdint.h>

// ---------------- constants ----------------
#define T_STEPS 1000
#define SDIM    128
#define ADIM    32
#define HID     256
#define TDIM    16
#define KPX     40                     // padded K stride for x tile (32 used)
#define KPH     264                    // padded K stride for hidden tiles (256 used)
                                       // NOTE: must stay ≡ 0 mod 8 ushorts (16B) so
                                       // ds_read_b128 alignment holds (KPH=268 broke
                                       // this: b128 reads split, 2x slowdown, r13)
#define W0P     20                     // padded row stride (dwords) for w0l in LDS

typedef __attribute__((ext_vector_type(8))) short short8;   // 8 bf16 (4 VGPRs)
typedef __attribute__((ext_vector_type(4))) float f32x4;    // MFMA accumulator
typedef __attribute__((ext_vector_type(4))) int   i32x4;

#define MFMA(A, B, C) __builtin_amdgcn_mfma_f32_16x16x32_bf16((A), (B), (C), 0, 0, 0)

// Barrier that drains LDS ops but leaves global loads (prefetches) in flight.
__device__ __forceinline__ void barrier_lgkm() {
  asm volatile("s_waitcnt lgkmcnt(0)" ::: "memory");
  __builtin_amdgcn_s_barrier();
  asm volatile("" ::: "memory");
}

// ---------------- bf16 helpers (RNE) ----------------
__device__ __forceinline__ unsigned short f2bf(float f) {
  uint32_t u = __float_as_uint(f);
  u = u + 0x7FFFu + ((u >> 16) & 1u);
  return (unsigned short)(u >> 16);
}
__device__ __forceinline__ float bf2f(unsigned short h) {
  return __uint_as_float(((uint32_t)h) << 16);
}

// ---------------- threefry2x32 (exact JAX semantics) ----------------
__device__ __forceinline__ uint32_t rotl32(uint32_t v, int d) {
  return (v << d) | (v >> (32 - d));
}
__device__ __forceinline__ void threefry2x32(uint32_t k0, uint32_t k1,
                                             uint32_t x0, uint32_t x1,
                                             uint32_t& o0, uint32_t& o1) {
  uint32_t ks0 = k0, ks1 = k1, ks2 = k0 ^ k1 ^ 0x1BD11BDAu;
  x0 += ks0; x1 += ks1;
#define TF_ROUND(r) { x0 += x1; x1 = rotl32(x1, (r)); x1 ^= x0; }
  TF_ROUND(13) TF_ROUND(15) TF_ROUND(26) TF_ROUND(6)
  x0 += ks1; x1 += ks2 + 1u;
  TF_ROUND(17) TF_ROUND(29) TF_ROUND(16) TF_ROUND(24)
  x0 += ks2; x1 += ks0 + 2u;
  TF_ROUND(13) TF_ROUND(15) TF_ROUND(26) TF_ROUND(6)
  x0 += ks0; x1 += ks1 + 3u;
  TF_ROUND(17) TF_ROUND(29) TF_ROUND(16) TF_ROUND(24)
  x0 += ks1; x1 += ks2 + 4u;
  TF_ROUND(13) TF_ROUND(15) TF_ROUND(26) TF_ROUND(6)
  x0 += ks2; x1 += ks0 + 5u;
#undef TF_ROUND
  o0 = x0; o1 = x1;
}
__device__ __forceinline__ uint32_t random_bits32_partitionable(uint32_t k0, uint32_t k1,
                                                               uint32_t j) {
  uint32_t o0, o1;
  threefry2x32(k0, k1, 0u, j, o0, o1);
  return o0 ^ o1;
}

// ---------------- XLA ErfInv (f32 Giles polynomial) ----------------
__device__ __forceinline__ float erfinv_f32(float x) {
  float w = -log1pf(-(x * x));
  float p;
  if (w < 5.0f) {
    w = w - 2.5f;
    p = 2.81022636e-08f;
    p = fmaf(p, w, 3.43273939e-07f);
    p = fmaf(p, w, -3.5233877e-06f);
    p = fmaf(p, w, -4.39150654e-06f);
    p = fmaf(p, w, 0.00021858087f);
    p = fmaf(p, w, -0.00125372503f);
    p = fmaf(p, w, -0.00417768164f);
    p = fmaf(p, w, 0.246640727f);
    p = fmaf(p, w, 1.50140941f);
  } else {
    w = sqrtf(w) - 3.0f;
    p = -0.000200214257f;
    p = fmaf(p, w, 0.000100950558f);
    p = fmaf(p, w, 0.00134934322f);
    p = fmaf(p, w, -0.00367342844f);
    p = fmaf(p, w, 0.00573950773f);
    p = fmaf(p, w, -0.0076224613f);
    p = fmaf(p, w, 0.00943887047f);
    p = fmaf(p, w, 1.00167406f);
    p = fmaf(p, w, 2.83297682f);
  }
  return p * x;
}
__device__ __forceinline__ float bits_to_normal(uint32_t bits) {
  float f = __uint_as_float((bits >> 9) | 0x3F800000u) - 1.0f;   // [0,1)
  float u = f * 2.0f + (-0.99999994f);
  u = fmaxf(-0.99999994f, u);
  return 1.41421356237309515f * erfinv_f32(u);   // sqrt(2) as f32
}

// mish(x) = x * t/(t+2), t = e^x (e^x + 2)
// FAST variant: v_exp_f32 (~2ulp) + v_rcp_f32 (~1ulp) instead of libm expf +
// IEEE div (saves ~29 VALU/call, 12 calls/thread/iter). Perturbation ~5e-7
// relative, 4 orders below bf16 quantization. (r15)
__device__ __forceinline__ float mish_f(float x) {
  float e = __expf(fminf(x, 20.0f));
  float t = fmaf(e, e, 2.0f * e);
  return x * t * __builtin_amdgcn_rcpf(t + 2.0f);
}

// ---------------- precompute: tf_all[1000][16], coefs[5][1000], keys[1000][2] -----
__global__ __launch_bounds__(64)
void precompute_kernel(const float* __restrict__ w_t1, const float* __restrict__ b_t1,
                       const float* __restrict__ w_t2, const float* __restrict__ b_t2,
                       float* __restrict__ tf_all, float* __restrict__ coefs,
                       uint32_t* __restrict__ keys) {
  const int i = blockIdx.x;
  const int j = threadIdx.x;
  const float tv = (float)i;
  __shared__ float hid[32];
  const float CF = (float)(-1.3157629102823120);  // -log(10000)/7
  if (j < 32) {
    float acc = b_t1[j];
#pragma unroll
    for (int k = 0; k < 16; ++k) {
      int kf = (k < 8) ? k : (k - 8);
      float fr = expf((float)kf * CF);
      float ang = tv * fr;
      float te = (k < 8) ? sinf(ang) : cosf(ang);
      acc = fmaf(te, w_t1[k * 32 + j], acc);
    }
    hid[j] = mish_f(acc);
  }
  __syncthreads();
  if (j < 16) {
    float acc = b_t2[j];
#pragma unroll
    for (int k2 = 0; k2 < 32; ++k2) acc = fmaf(hid[k2], w_t2[k2 * 16 + j], acc);
    tf_all[i * TDIM + j] = acc;
  }
  if (j == 0) {
    double t = (double)(i + 1);
    double ac  = exp(-0.1 * t / 1000.0 - 4.95 * t * t / 1.0e6);
    double acp = (i == 0) ? 1.0
        : exp(-0.1 * (t - 1.0) / 1000.0 - 4.95 * (t - 1.0) * (t - 1.0) / 1.0e6);
    double alpha = exp(-0.1 / 1000.0 - 4.95 * (2.0 * t - 1.0) / 1.0e6);
    double beta = 1.0 - alpha;
    double sr   = sqrt(1.0 / ac);
    double srm1 = sqrt(1.0 / ac - 1.0);
    double c1 = beta * sqrt(acp) / (1.0 - ac);
    double c2 = (1.0 - acp) * sqrt(alpha) / (1.0 - ac);
    double pv = beta * (1.0 - acp) / (1.0 - ac);
    double lv = log(fmax(pv, 1.0e-20));
    coefs[0 * T_STEPS + i] = (float)sr;
    coefs[1 * T_STEPS + i] = (float)srm1;
    coefs[2 * T_STEPS + i] = (float)c1;
    coefs[3 * T_STEPS + i] = (float)c2;
    float lvf = (float)lv;
    coefs[4 * T_STEPS + i] = expf(0.5f * lvf);
    uint32_t o0, o1;
    threefry2x32(0u, 1u, 0u, (uint32_t)i, o0, o1);
    keys[2 * i]     = o0;
    keys[2 * i + 1] = o1;
  }
}

// -------- prep: MFMA B-fragment hi/lo layout + w0tf transpose ---------------------
__global__ __launch_bounds__(64)
void prep_frags(const float* __restrict__ w0, const float* __restrict__ w1,
                const float* __restrict__ w2, const float* __restrict__ wf,
                unsigned short* __restrict__ f0x, unsigned short* __restrict__ f0s,
                unsigned short* __restrict__ f1, unsigned short* __restrict__ f2,
                unsigned short* __restrict__ ff, float* __restrict__ w0tf) {
  const int bid = blockIdx.x;   // 0..355
  const int l = threadIdx.x;    // 0..63
  if (bid >= 352) {             // w0tf transpose
    int n = (bid - 352) * 64 + l;
#pragma unroll
    for (int c = 0; c < 16; ++c) w0tf[n * 16 + c] = w0[(32 + c) * HID + n];
    return;
  }
  const float* W; unsigned short* F; int NT, N, idx, rowoff, Kmax;
  if (bid < 16)       { W = w0; F = f0x; NT = 16; N = 256; idx = bid;       rowoff = 0;  Kmax = 32;  }
  else if (bid < 80)  { W = w0; F = f0s; NT = 16; N = 256; idx = bid - 16;  rowoff = 48; Kmax = 128; }
  else if (bid < 208) { W = w1; F = f1;  NT = 16; N = 256; idx = bid - 80;  rowoff = 0;  Kmax = 256; }
  else if (bid < 336) { W = w2; F = f2;  NT = 16; N = 256; idx = bid - 208; rowoff = 0;  Kmax = 256; }
  else                { W = wf; F = ff;  NT = 2;  N = 32;  idx = bid - 336; rowoff = 0;  Kmax = 256; }
  const int kt = idx / NT, nt = idx % NT;
  const int n = nt * 16 + (l & 15);
  const int kbase = kt * 32 + (l >> 4) * 8;
  unsigned short* dst = F + idx * 1024 + l * 8;
#pragma unroll
  for (int j = 0; j < 8; ++j) {
    int k = kbase + j;
    float v = (k < Kmax) ? W[(rowoff + k) * N + n] : 0.0f;
    unsigned short h = f2bf(v);
    dst[j]       = h;
    dst[512 + j] = f2bf(v - bf2f(h));
  }
}

// ---------------- persistent main kernel ------------------------------------------
// Grid 256 (1 block/CU), 1024 threads (16 waves), wave w owns nt-column w.
// LDS-resident: ff (32K), w0tf padded (20K), f2 kt0-1 (64K). F1 in AGPRs (pinned).
// Barriers B1..B4 drain lgkmcnt only -> global prefetches survive barriers.
// RNG distributed: threads 0-511 compute nzv into s_nz during L2 phase; LF+posterior
// fused on waves 14,15 reads s_nz. 4 barriers/iter. Fast mish (r15).
__global__ __launch_bounds__(1024)
void diffusion_main(const float* __restrict__ state, const float* __restrict__ x_init,
                    const float* __restrict__ b0, const float* __restrict__ b1,
                    const float* __restrict__ b2, const float* __restrict__ bf,
                    const unsigned short* __restrict__ f0x, const unsigned short* __restrict__ f0s,
                    const unsigned short* __restrict__ f1, const unsigned short* __restrict__ f2,
                    const unsigned short* __restrict__ ff,
                    const float* __restrict__ tf_all, const float* __restrict__ w0tf,
                    const float* __restrict__ coefs,
                    const uint32_t* __restrict__ keys, float* __restrict__ out) {
  __shared__ __align__(16) unsigned short a0h[16][KPX], a0l[16][KPX];
  __shared__ __align__(16) unsigned short aAh[16][KPH], aAl[16][KPH];
  __shared__ __align__(16) unsigned short aBh[16][KPH], aBl[16][KPH];
  __shared__ __align__(16) unsigned short ffl[16 * 1024];   // ff resident (32 KB)
  __shared__ __align__(16) unsigned short f2l[32 * 1024];   // f2 kt0,1 resident (64 KB)
  __shared__ __align__(16) float w0l[HID * W0P];            // w0tf resident, padded (20 KB)
  __shared__ float s_x[16][ADIM];
  __shared__ float s_nz[16][33];                            // distributed RNG output

  const int tid = threadIdx.x;          // 0..1023
  const int base = blockIdx.x * 8;
  const int l = tid & 63;               // lane
  const int w = tid >> 6;               // wave 0..15
  const int lrow = l & 15;
  const int quad = l >> 4;              // 0..3
  const int nt = w;                     // one col-tile per wave

  // ---- stage x_init (16x32 = 512 elems; tid<512) ----
  if (tid < 512) {
    int r = tid >> 5, d = tid & 31;
    int grow = (r < 8) ? (base + r) : (2048 + base + r - 8);
    float v = x_init[grow * ADIM + d];
    s_x[r][d] = v;
    unsigned short h = f2bf(v);
    a0h[r][d] = h; a0l[r][d] = f2bf(v - bf2f(h));
  }
  // ---- stage state into aA cols 0..127 (one-time) ----
  for (int idx = tid; idx < 16 * SDIM; idx += 1024) {
    int r = idx >> 7, c = idx & 127;
    int grow = (r < 8) ? (base + r) : (2048 + base + r - 8);
    float v = state[grow * SDIM + c];
    unsigned short h = f2bf(v);
    aAh[r][c] = h; aAl[r][c] = f2bf(v - bf2f(h));
  }
  // ---- copy ff (32 KB), f2 kt0,1 (64 KB) into LDS once ----
  {
    const int4* src = reinterpret_cast<const int4*>(ff);
    int4* dst = reinterpret_cast<int4*>(ffl);
    dst[tid] = src[tid];
    dst[tid + 1024] = src[tid + 1024];
  }
  {
    const int4* src = reinterpret_cast<const int4*>(f2);
    int4* dst = reinterpret_cast<int4*>(f2l);
#pragma unroll
    for (int i = 0; i < 4; ++i) dst[tid + i * 1024] = src[tid + i * 1024];
  }
  // ---- copy w0tf into padded LDS rows (stride W0P dwords, bank-spread) ----
  for (int idx = tid; idx < HID * TDIM; idx += 1024) {
    int n = idx >> 4, c = idx & 15;
    w0l[n * W0P + c] = w0tf[idx];
  }

  const float b0v = b0[nt * 16 + lrow];
  const float b1v = b1[nt * 16 + lrow];
  const float b2v = b2[nt * 16 + lrow];
  const float bfv = (w >= 14) ? bf[(w - 14) * 16 + lrow] : 0.0f;
  __syncthreads();

  // ---- one-time: sacc = state-part of layer0 for this wave's nt ----
  f32x4 sacc = {0.f, 0.f, 0.f, 0.f};
  {
    const unsigned short* aH = &aAh[0][0] + lrow * KPH + quad * 8;
    const unsigned short* aL = &aAl[0][0] + lrow * KPH + quad * 8;
#pragma unroll
    for (int kt = 0; kt < 4; ++kt) {
      short8 ah = *reinterpret_cast<const short8*>(aH + kt * 32);
      short8 al = *reinterpret_cast<const short8*>(aL + kt * 32);
      const unsigned short* p = f0s + (kt * 16 + nt) * 1024 + l * 8;
      short8 bh = *reinterpret_cast<const short8*>(p);
      short8 bl = *reinterpret_cast<const short8*>(p + 512);
      sacc = MFMA(ah, bh, sacc);
      sacc = MFMA(al, bh, sacc);
      sacc = MFMA(ah, bl, sacc);
    }
  }

  // ---- persistent loop-invariant x fragments (kt=0 of layer0, this nt) ----
  short8 Xh, Xl;
  {
    const unsigned short* p = f0x + nt * 1024 + l * 8;
    Xh = *reinterpret_cast<const short8*>(p);
    Xl = *reinterpret_cast<const short8*>(p + 512);
  }

  // ---- F1 slice -> AGPRs (64 dwords), written once, read per iter ----
#define DECL_AG(k) int AH0_##k, AH1_##k, AH2_##k, AH3_##k, \
                       AL0_##k, AL1_##k, AL2_##k, AL3_##k;
  DECL_AG(0) DECL_AG(1) DECL_AG(2) DECL_AG(3)
  DECL_AG(4) DECL_AG(5) DECL_AG(6) DECL_AG(7)
#define LOAD_AG(k) { \
    i32x4 hv = *reinterpret_cast<const i32x4*>(f1 + ((k) * 16 + nt) * 1024 + l * 8); \
    i32x4 lv = *reinterpret_cast<const i32x4*>(f1 + ((k) * 16 + nt) * 1024 + 512 + l * 8); \
    asm volatile("v_accvgpr_write_b32 %0, %1" : "=a"(AH0_##k) : "v"(hv[0])); \
    asm volatile("v_accvgpr_write_b32 %0, %1" : "=a"(AH1_##k) : "v"(hv[1])); \
    asm volatile("v_accvgpr_write_b32 %0, %1" : "=a"(AH2_##k) : "v"(hv[2])); \
    asm volatile("v_accvgpr_write_b32 %0, %1" : "=a"(AH3_##k) : "v"(hv[3])); \
    asm volatile("v_accvgpr_write_b32 %0, %1" : "=a"(AL0_##k) : "v"(lv[0])); \
    asm volatile("v_accvgpr_write_b32 %0, %1" : "=a"(AL1_##k) : "v"(lv[1])); \
    asm volatile("v_accvgpr_write_b32 %0, %1" : "=a"(AL2_##k) : "v"(lv[2])); \
    asm volatile("v_accvgpr_write_b32 %0, %1" : "=a"(AL3_##k) : "v"(lv[3])); }
  LOAD_AG(0) LOAD_AG(1) LOAD_AG(2) LOAD_AG(3)
  LOAD_AG(4) LOAD_AG(5) LOAD_AG(6) LOAD_AG(7)

  // ---- per-lane tf-bias dot (16 f32 FMAs; weights from padded LDS) ----
  float bt;
  auto compute_bt = [&](int tt) {
    const float4* tfr = reinterpret_cast<const float4*>(tf_all + tt * TDIM);
    const float4* wA = reinterpret_cast<const float4*>(&w0l[(nt * 16 + lrow) * W0P]);
    float a = 0.0f;
#pragma unroll
    for (int q = 0; q < 4; ++q) {
      float4 tq = tfr[q];
      float4 wa = wA[q];
      a = fmaf(tq.x, wa.x, a);
      a = fmaf(tq.y, wa.y, a);
      a = fmaf(tq.z, wa.z, a);
      a = fmaf(tq.w, wa.w, a);
    }
    bt = a;
  };
  compute_bt(T_STEPS - 1);

  // epilogue: acc -> mish -> hi/lo LDS tile (single nt column)
  auto epi_store = [&](const f32x4& acc, float bA,
                       unsigned short* dH, unsigned short* dL) {
#pragma unroll
    for (int reg = 0; reg < 4; ++reg) {
      int orow = quad * 4 + reg;
      float v = mish_f(acc[reg] + bA);
      unsigned short h = f2bf(v);
      dH[orow * KPH + nt * 16 + lrow] = h;
      dL[orow * KPH + nt * 16 + lrow] = f2bf(v - bf2f(h));
    }
  };

  __syncthreads();  // B0 (full drain, once)

  for (int t = T_STEPS - 1; t >= 0; --t) {
    float sr  = coefs[0 * T_STEPS + t];
    float srm = coefs[1 * T_STEPS + t];
    float c1  = coefs[2 * T_STEPS + t];
    float c2  = coefs[3 * T_STEPS + t];
    float sig = (t != 0) ? coefs[4 * T_STEPS + t] : 0.0f;
    uint32_t k0 = keys[2 * t], k1 = keys[2 * t + 1];

    // ---- L0: x-part only (1 kt), acc starts from persistent state part ----
    {
      f32x4 acc = sacc;
      short8 ah = *reinterpret_cast<const short8*>(&a0h[0][0] + lrow * KPX + quad * 8);
      short8 al = *reinterpret_cast<const short8*>(&a0l[0][0] + lrow * KPX + quad * 8);
      acc = MFMA(ah, Xh, acc);
      acc = MFMA(al, Xh, acc);
      acc = MFMA(ah, Xl, acc);
      epi_store(acc, b0v + bt, &aAh[0][0], &aAl[0][0]);
    }
    barrier_lgkm();  // B1: aA ready (global prefetches stay in flight)

    // ---- L1: weights from AGPRs (zero memory traffic); prefetch F2 kt2 ----
    short8 P2h, P2l;
    {
      f32x4 acc = {0.f, 0.f, 0.f, 0.f};
      const unsigned short* aH = &aAh[0][0] + lrow * KPH + quad * 8;
      const unsigned short* aL = &aAl[0][0] + lrow * KPH + quad * 8;
#define L1_STEP(k) { \
      int h0, h1, h2, h3, lo0, lo1, lo2, lo3; \
      asm volatile("v_accvgpr_read_b32 %0, %1" : "=v"(h0)  : "a"(AH0_##k)); \
      asm volatile("v_accvgpr_read_b32 %0, %1" : "=v"(h1)  : "a"(AH1_##k)); \
      asm volatile("v_accvgpr_read_b32 %0, %1" : "=v"(h2)  : "a"(AH2_##k)); \
      asm volatile("v_accvgpr_read_b32 %0, %1" : "=v"(h3)  : "a"(AH3_##k)); \
      asm volatile("v_accvgpr_read_b32 %0, %1" : "=v"(lo0) : "a"(AL0_##k)); \
      asm volatile("v_accvgpr_read_b32 %0, %1" : "=v"(lo1) : "a"(AL1_##k)); \
      asm volatile("v_accvgpr_read_b32 %0, %1" : "=v"(lo2) : "a"(AL2_##k)); \
      asm volatile("v_accvgpr_read_b32 %0, %1" : "=v"(lo3) : "a"(AL3_##k)); \
      i32x4 hv = {h0, h1, h2, h3}; \
      i32x4 lv = {lo0, lo1, lo2, lo3}; \
      short8 bh = *reinterpret_cast<short8*>(&hv); \
      short8 bl = *reinterpret_cast<short8*>(&lv); \
      short8 ah = *reinterpret_cast<const short8*>(aH + (k) * 32); \
      short8 al = *reinterpret_cast<const short8*>(aL + (k) * 32); \
      acc = MFMA(ah, bh, acc); \
      acc = MFMA(al, bh, acc); \
      acc = MFMA(ah, bl, acc); }
      L1_STEP(0) L1_STEP(1) L1_STEP(2) L1_STEP(3)
      L1_STEP(4) L1_STEP(5) L1_STEP(6) L1_STEP(7)
#undef L1_STEP
      {
        const unsigned short* p = f2 + (2 * 16 + nt) * 1024 + l * 8;
        P2h = *reinterpret_cast<const short8*>(p);
        P2l = *reinterpret_cast<const short8*>(p + 512);
      }
      epi_store(acc, b1v, &aBh[0][0], &aBl[0][0]);
    }
    barrier_lgkm();  // B2: aB ready (P2 still in flight)

    // ---- distributed RNG: threads 0-511, one nzv each (hides in L2 stalls) ----
    if (tid < 512) {
      int d = tid & 31, r = tid >> 5;
      int grow = (r < 8) ? (base + r) : (2048 + base + r - 8);
      uint32_t jflat = (uint32_t)(grow * ADIM + d);
      s_nz[r][d] = bits_to_normal(random_bits32_partitionable(k0, k1, jflat));
    }

    // ---- L2: kt0,1 from LDS; kt2 from prefetch; kt3..7 streamed ----
    {
      f32x4 acc = {0.f, 0.f, 0.f, 0.f};
      const unsigned short* aH = &aBh[0][0] + lrow * KPH + quad * 8;
      const unsigned short* aL = &aBl[0][0] + lrow * KPH + quad * 8;
#pragma unroll
      for (int kt = 0; kt < 2; ++kt) {
        const unsigned short* p = &f2l[0] + (kt * 16 + nt) * 1024 + l * 8;
        short8 bh = *reinterpret_cast<const short8*>(p);
        short8 bl = *reinterpret_cast<const short8*>(p + 512);
        short8 ah = *reinterpret_cast<const short8*>(aH + kt * 32);
        short8 al = *reinterpret_cast<const short8*>(aL + kt * 32);
        acc = MFMA(ah, bh, acc);
        acc = MFMA(al, bh, acc);
        acc = MFMA(ah, bl, acc);
      }
      {  // kt = 2 from prefetch
        short8 ah = *reinterpret_cast<const short8*>(aH + 2 * 32);
        short8 al = *reinterpret_cast<const short8*>(aL + 2 * 32);
        acc = MFMA(ah, P2h, acc);
        acc = MFMA(al, P2h, acc);
        acc = MFMA(ah, P2l, acc);
      }
#pragma unroll
      for (int kt = 3; kt < 8; ++kt) {
        const unsigned short* p = f2 + (kt * 16 + nt) * 1024 + l * 8;
        short8 bh = *reinterpret_cast<const short8*>(p);
        short8 bl = *reinterpret_cast<const short8*>(p + 512);
        short8 ah = *reinterpret_cast<const short8*>(aH + kt * 32);
        short8 al = *reinterpret_cast<const short8*>(aL + kt * 32);
        acc = MFMA(ah, bh, acc);
        acc = MFMA(al, bh, acc);
        acc = MFMA(ah, bl, acc);
      }
      epi_store(acc, b2v, &aAh[0][0], &aAl[0][0]);
    }
    barrier_lgkm();  // B3: aA(L2 out) + s_nz ready

    // ---- LF + fused posterior on waves 14,15 (eps stays in registers) ----
    if (w >= 14) {
      f32x4 acc = {0.f, 0.f, 0.f, 0.f};
      const unsigned short* aH = &aAh[0][0] + lrow * KPH + quad * 8;
      const unsigned short* aL = &aAl[0][0] + lrow * KPH + quad * 8;
      const int wf2 = w - 14;
#pragma unroll
      for (int kt = 0; kt < 8; ++kt) {
        const unsigned short* p = &ffl[0] + (kt * 2 + wf2) * 1024 + l * 8;
        short8 bh = *reinterpret_cast<const short8*>(p);
        short8 bl = *reinterpret_cast<const short8*>(p + 512);
        short8 ah = *reinterpret_cast<const short8*>(aH + kt * 32);
        short8 al = *reinterpret_cast<const short8*>(aL + kt * 32);
        acc = MFMA(ah, bh, acc);
        acc = MFMA(al, bh, acc);
        acc = MFMA(ah, bl, acc);
      }
      const int d = wf2 * 16 + lrow;
#pragma unroll
      for (int reg = 0; reg < 4; ++reg) {
        int r = quad * 4 + reg;
        float eps = acc[reg] + bfv;
        float nzv = s_nz[r][d];
        float xv = s_x[r][d];
        float x0v = fminf(fmaxf(sr * xv - srm * eps, -1.0f), 1.0f);
        float xn = c1 * x0v + c2 * xv + sig * nzv;
        s_x[r][d] = xn;
        unsigned short h = f2bf(xn);
        a0h[r][d] = h; a0l[r][d] = f2bf(xn - bf2f(h));
      }
    }
    // next iteration's tf-bias (all waves; overlaps LF+posterior)
    compute_bt((t > 0) ? (t - 1) : 0);
    barrier_lgkm();  // B4: a0/s_x ready for next L0
  }

  // ---- output ----
  if (tid < 512) {
    int r = tid >> 5, d = tid & 31;
    int grow = (r < 8) ? (base + r) : (2048 + base + r - 8);
    out[grow * ADIM + d] = fminf(fmaxf(s_x[r][d], -1.0f), 1.0f);
  }
}

// ---------------- launcher ----------------
extern "C" void kernel_launch(void* const* d_in, const int* in_sizes, int n_in,
                              void* d_out, int out_size, void* d_ws, size_t ws_size,
                              hipStream_t stream) {
  const float* state = (const float*)d_in[0];
  const float* x_init = (const float*)d_in[1];
  const float* w_t1 = (const float*)d_in[2];
  const float* b_t1 = (const float*)d_in[3];
  const float* w_t2 = (const float*)d_in[4];
  const float* b_t2 = (const float*)d_in[5];
  const float* w0 = (const float*)d_in[6];
  const float* b0 = (const float*)d_in[7];
  const float* w1 = (const float*)d_in[8];
  const float* b1 = (const float*)d_in[9];
  const float* w2 = (const float*)d_in[10];
  const float* b2 = (const float*)d_in[11];
  const float* wf = (const float*)d_in[12];
  const float* bf = (const float*)d_in[13];
  float* out = (float*)d_out;

  // ws layout (f32 units unless noted), total ~829 KB:
  //   tf_all[16000] | w0tf[4096] | coefs[5000] | keys[2000] u32
  //   | f0x[16K ush] | f0s[64K] | f1[128K] | f2[128K] | ff[16K]
  float* tf_all = (float*)d_ws;
  float* w0tf = tf_all + T_STEPS * TDIM;
  float* coefs = w0tf + HID * TDIM;
  uint32_t* keys = (uint32_t*)(coefs + 5 * T_STEPS);
  unsigned short* f0x = (unsigned short*)(keys + 2 * T_STEPS);
  unsigned short* f0s = f0x + 16 * 1024;
  unsigned short* f1 = f0s + 64 * 1024;
  unsigned short* f2 = f1 + 128 * 1024;
  unsigned short* ff = f2 + 128 * 1024;

  precompute_kernel<<<T_STEPS, 64, 0, stream>>>(w_t1, b_t1, w_t2, b_t2,
                                                tf_all, coefs, keys);
  prep_frags<<<356, 64, 0, stream>>>(w0, w1, w2, wf, f0x, f0s, f1, f2, ff, w0tf);
  diffusion_main<<<256, 1024, 0, stream>>>(state, x_init, b0, b1, b2, bf,
                                           f0x, f0s, f1, f2, ff,
                                           tf_all, w0tf, coefs, keys, out);
}

// Round 16
// 6713.255 us; speedup vs baseline: 3.0607x; 1.0420x over previous
//
#include <hip/hip_runtime.h>
#include <stdint.h>

// ---------------- constants ----------------
#define T_STEPS 1000
#define SDIM    128
#define ADIM    32
#define HID     256
#define TDIM    16
#define KPX     40                     // padded K stride for x tile (32 used)
#define KPH     264                    // padded K stride for hidden tiles (256 used)
                                       // NOTE: must stay ≡ 0 mod 8 ushorts (16B) so
                                       // ds_read_b128 alignment holds (KPH=268 broke
                                       // this: b128 reads split, 2x slowdown, r13)
#define W0P     20                     // padded row stride (dwords) for w0l in LDS

typedef __attribute__((ext_vector_type(8))) short short8;   // 8 bf16 (4 VGPRs)
typedef __attribute__((ext_vector_type(4))) float f32x4;    // MFMA accumulator
typedef __attribute__((ext_vector_type(4))) int   i32x4;

#define MFMA(A, B, C) __builtin_amdgcn_mfma_f32_16x16x32_bf16((A), (B), (C), 0, 0, 0)

// Barrier that drains LDS ops but leaves global loads (prefetches) in flight.
__device__ __forceinline__ void barrier_lgkm() {
  asm volatile("s_waitcnt lgkmcnt(0)" ::: "memory");
  __builtin_amdgcn_s_barrier();
  asm volatile("" ::: "memory");
}

// ---------------- bf16 helpers ----------------
// RNE (used for hi plane / staging)
__device__ __forceinline__ unsigned short f2bf(float f) {
  uint32_t u = __float_as_uint(f);
  u = u + 0x7FFFu + ((u >> 16) & 1u);
  return (unsigned short)(u >> 16);
}
__device__ __forceinline__ float bf2f(unsigned short h) {
  return __uint_as_float(((uint32_t)h) << 16);
}
// Truncating convert for the LO plane only (residual ≤ 2^-9|v|; trunc-vs-RNE
// differs ≤ 2^-17|v|, same order as the split scheme's inherent error). r16
__device__ __forceinline__ unsigned short f2bf_trunc(float f) {
  return (unsigned short)(__float_as_uint(f) >> 16);
}

// ---------------- threefry2x32 (exact JAX semantics) ----------------
__device__ __forceinline__ uint32_t rotl32(uint32_t v, int d) {
  return (v << d) | (v >> (32 - d));
}
__device__ __forceinline__ void threefry2x32(uint32_t k0, uint32_t k1,
                                             uint32_t x0, uint32_t x1,
                                             uint32_t& o0, uint32_t& o1) {
  uint32_t ks0 = k0, ks1 = k1, ks2 = k0 ^ k1 ^ 0x1BD11BDAu;
  x0 += ks0; x1 += ks1;
#define TF_ROUND(r) { x0 += x1; x1 = rotl32(x1, (r)); x1 ^= x0; }
  TF_ROUND(13) TF_ROUND(15) TF_ROUND(26) TF_ROUND(6)
  x0 += ks1; x1 += ks2 + 1u;
  TF_ROUND(17) TF_ROUND(29) TF_ROUND(16) TF_ROUND(24)
  x0 += ks2; x1 += ks0 + 2u;
  TF_ROUND(13) TF_ROUND(15) TF_ROUND(26) TF_ROUND(6)
  x0 += ks0; x1 += ks1 + 3u;
  TF_ROUND(17) TF_ROUND(29) TF_ROUND(16) TF_ROUND(24)
  x0 += ks1; x1 += ks2 + 4u;
  TF_ROUND(13) TF_ROUND(15) TF_ROUND(26) TF_ROUND(6)
  x0 += ks2; x1 += ks0 + 5u;
#undef TF_ROUND
  o0 = x0; o1 = x1;
}
__device__ __forceinline__ uint32_t random_bits32_partitionable(uint32_t k0, uint32_t k1,
                                                               uint32_t j) {
  uint32_t o0, o1;
  threefry2x32(k0, k1, 0u, j, o0, o1);
  return o0 ^ o1;
}

// ---------------- XLA ErfInv (f32 Giles polynomial), fast-log variant ----------
// w = -log(1-x^2): fmaf(x,-x,1) has ONE rounding (no cancellation), v_log ~1ulp.
// nzv perturbation ≲1e-6 absolute — 2 orders below the bf16 error floor. (r16)
__device__ __forceinline__ float erfinv_f32(float x) {
  float w = -__logf(fmaf(x, -x, 1.0f));
  float p;
  if (w < 5.0f) {
    w = w - 2.5f;
    p = 2.81022636e-08f;
    p = fmaf(p, w, 3.43273939e-07f);
    p = fmaf(p, w, -3.5233877e-06f);
    p = fmaf(p, w, -4.39150654e-06f);
    p = fmaf(p, w, 0.00021858087f);
    p = fmaf(p, w, -0.00125372503f);
    p = fmaf(p, w, -0.00417768164f);
    p = fmaf(p, w, 0.246640727f);
    p = fmaf(p, w, 1.50140941f);
  } else {
    w = sqrtf(w) - 3.0f;
    p = -0.000200214257f;
    p = fmaf(p, w, 0.000100950558f);
    p = fmaf(p, w, 0.00134934322f);
    p = fmaf(p, w, -0.00367342844f);
    p = fmaf(p, w, 0.00573950773f);
    p = fmaf(p, w, -0.0076224613f);
    p = fmaf(p, w, 0.00943887047f);
    p = fmaf(p, w, 1.00167406f);
    p = fmaf(p, w, 2.83297682f);
  }
  return p * x;
}
__device__ __forceinline__ float bits_to_normal(uint32_t bits) {
  float f = __uint_as_float((bits >> 9) | 0x3F800000u) - 1.0f;   // [0,1)
  float u = f * 2.0f + (-0.99999994f);
  u = fmaxf(-0.99999994f, u);
  return 1.41421356237309515f * erfinv_f32(u);   // sqrt(2) as f32
}

// mish(x) = x * t/(t+2), t = e^x (e^x + 2)
// FAST variant: v_exp_f32 (~2ulp) + v_rcp_f32 (~1ulp). (r15, verified)
__device__ __forceinline__ float mish_f(float x) {
  float e = __expf(fminf(x, 20.0f));
  float t = fmaf(e, e, 2.0f * e);
  return x * t * __builtin_amdgcn_rcpf(t + 2.0f);
}

// ---------------- precompute: tf_all[1000][16], coefs[5][1000], keys[1000][2] -----
__global__ __launch_bounds__(64)
void precompute_kernel(const float* __restrict__ w_t1, const float* __restrict__ b_t1,
                       const float* __restrict__ w_t2, const float* __restrict__ b_t2,
                       float* __restrict__ tf_all, float* __restrict__ coefs,
                       uint32_t* __restrict__ keys) {
  const int i = blockIdx.x;
  const int j = threadIdx.x;
  const float tv = (float)i;
  __shared__ float hid[32];
  const float CF = (float)(-1.3157629102823120);  // -log(10000)/7
  if (j < 32) {
    float acc = b_t1[j];
#pragma unroll
    for (int k = 0; k < 16; ++k) {
      int kf = (k < 8) ? k : (k - 8);
      float fr = expf((float)kf * CF);
      float ang = tv * fr;
      float te = (k < 8) ? sinf(ang) : cosf(ang);
      acc = fmaf(te, w_t1[k * 32 + j], acc);
    }
    // precompute runs once; keep libm-precision mish here (matches r14 state
    // because r15's fast mish was also used here and passed — stay consistent)
    float e = __expf(fminf(acc, 20.0f));
    float t = fmaf(e, e, 2.0f * e);
    hid[j] = acc * t * __builtin_amdgcn_rcpf(t + 2.0f);
  }
  __syncthreads();
  if (j < 16) {
    float acc = b_t2[j];
#pragma unroll
    for (int k2 = 0; k2 < 32; ++k2) acc = fmaf(hid[k2], w_t2[k2 * 16 + j], acc);
    tf_all[i * TDIM + j] = acc;
  }
  if (j == 0) {
    double t = (double)(i + 1);
    double ac  = exp(-0.1 * t / 1000.0 - 4.95 * t * t / 1.0e6);
    double acp = (i == 0) ? 1.0
        : exp(-0.1 * (t - 1.0) / 1000.0 - 4.95 * (t - 1.0) * (t - 1.0) / 1.0e6);
    double alpha = exp(-0.1 / 1000.0 - 4.95 * (2.0 * t - 1.0) / 1.0e6);
    double beta = 1.0 - alpha;
    double sr   = sqrt(1.0 / ac);
    double srm1 = sqrt(1.0 / ac - 1.0);
    double c1 = beta * sqrt(acp) / (1.0 - ac);
    double c2 = (1.0 - acp) * sqrt(alpha) / (1.0 - ac);
    double pv = beta * (1.0 - acp) / (1.0 - ac);
    double lv = log(fmax(pv, 1.0e-20));
    coefs[0 * T_STEPS + i] = (float)sr;
    coefs[1 * T_STEPS + i] = (float)srm1;
    coefs[2 * T_STEPS + i] = (float)c1;
    coefs[3 * T_STEPS + i] = (float)c2;
    float lvf = (float)lv;
    coefs[4 * T_STEPS + i] = expf(0.5f * lvf);
    uint32_t o0, o1;
    threefry2x32(0u, 1u, 0u, (uint32_t)i, o0, o1);
    keys[2 * i]     = o0;
    keys[2 * i + 1] = o1;
  }
}

// -------- prep: MFMA B-fragment hi/lo layout + w0tf transpose ---------------------
__global__ __launch_bounds__(64)
void prep_frags(const float* __restrict__ w0, const float* __restrict__ w1,
                const float* __restrict__ w2, const float* __restrict__ wf,
                unsigned short* __restrict__ f0x, unsigned short* __restrict__ f0s,
                unsigned short* __restrict__ f1, unsigned short* __restrict__ f2,
                unsigned short* __restrict__ ff, float* __restrict__ w0tf) {
  const int bid = blockIdx.x;   // 0..355
  const int l = threadIdx.x;    // 0..63
  if (bid >= 352) {             // w0tf transpose
    int n = (bid - 352) * 64 + l;
#pragma unroll
    for (int c = 0; c < 16; ++c) w0tf[n * 16 + c] = w0[(32 + c) * HID + n];
    return;
  }
  const float* W; unsigned short* F; int NT, N, idx, rowoff, Kmax;
  if (bid < 16)       { W = w0; F = f0x; NT = 16; N = 256; idx = bid;       rowoff = 0;  Kmax = 32;  }
  else if (bid < 80)  { W = w0; F = f0s; NT = 16; N = 256; idx = bid - 16;  rowoff = 48; Kmax = 128; }
  else if (bid < 208) { W = w1; F = f1;  NT = 16; N = 256; idx = bid - 80;  rowoff = 0;  Kmax = 256; }
  else if (bid < 336) { W = w2; F = f2;  NT = 16; N = 256; idx = bid - 208; rowoff = 0;  Kmax = 256; }
  else                { W = wf; F = ff;  NT = 2;  N = 32;  idx = bid - 336; rowoff = 0;  Kmax = 256; }
  const int kt = idx / NT, nt = idx % NT;
  const int n = nt * 16 + (l & 15);
  const int kbase = kt * 32 + (l >> 4) * 8;
  unsigned short* dst = F + idx * 1024 + l * 8;
#pragma unroll
  for (int j = 0; j < 8; ++j) {
    int k = kbase + j;
    float v = (k < Kmax) ? W[(rowoff + k) * N + n] : 0.0f;
    unsigned short h = f2bf(v);
    dst[j]       = h;
    dst[512 + j] = f2bf(v - bf2f(h));   // weights converted once: keep RNE
  }
}

// ---------------- persistent main kernel ------------------------------------------
// Grid 256 (1 block/CU), 1024 threads (16 waves), wave w owns nt-column w.
// LDS-resident: ff (32K), w0tf padded (20K), f2 kt0-1 (64K). F1 in AGPRs (pinned).
// Barriers B1..B4 drain lgkmcnt only -> global prefetches survive barriers.
// RNG distributed; LF+posterior fused on waves 14,15. 4 barriers/iter.
// Fast mish (r15) + fast log / truncated lo-plane (r16).
__global__ __launch_bounds__(1024)
void diffusion_main(const float* __restrict__ state, const float* __restrict__ x_init,
                    const float* __restrict__ b0, const float* __restrict__ b1,
                    const float* __restrict__ b2, const float* __restrict__ bf,
                    const unsigned short* __restrict__ f0x, const unsigned short* __restrict__ f0s,
                    const unsigned short* __restrict__ f1, const unsigned short* __restrict__ f2,
                    const unsigned short* __restrict__ ff,
                    const float* __restrict__ tf_all, const float* __restrict__ w0tf,
                    const float* __restrict__ coefs,
                    const uint32_t* __restrict__ keys, float* __restrict__ out) {
  __shared__ __align__(16) unsigned short a0h[16][KPX], a0l[16][KPX];
  __shared__ __align__(16) unsigned short aAh[16][KPH], aAl[16][KPH];
  __shared__ __align__(16) unsigned short aBh[16][KPH], aBl[16][KPH];
  __shared__ __align__(16) unsigned short ffl[16 * 1024];   // ff resident (32 KB)
  __shared__ __align__(16) unsigned short f2l[32 * 1024];   // f2 kt0,1 resident (64 KB)
  __shared__ __align__(16) float w0l[HID * W0P];            // w0tf resident, padded (20 KB)
  __shared__ float s_x[16][ADIM];
  __shared__ float s_nz[16][33];                            // distributed RNG output

  const int tid = threadIdx.x;          // 0..1023
  const int base = blockIdx.x * 8;
  const int l = tid & 63;               // lane
  const int w = tid >> 6;               // wave 0..15
  const int lrow = l & 15;
  const int quad = l >> 4;              // 0..3
  const int nt = w;                     // one col-tile per wave

  // ---- stage x_init (16x32 = 512 elems; tid<512) ----
  if (tid < 512) {
    int r = tid >> 5, d = tid & 31;
    int grow = (r < 8) ? (base + r) : (2048 + base + r - 8);
    float v = x_init[grow * ADIM + d];
    s_x[r][d] = v;
    unsigned short h = f2bf(v);
    a0h[r][d] = h; a0l[r][d] = f2bf(v - bf2f(h));
  }
  // ---- stage state into aA cols 0..127 (one-time) ----
  for (int idx = tid; idx < 16 * SDIM; idx += 1024) {
    int r = idx >> 7, c = idx & 127;
    int grow = (r < 8) ? (base + r) : (2048 + base + r - 8);
    float v = state[grow * SDIM + c];
    unsigned short h = f2bf(v);
    aAh[r][c] = h; aAl[r][c] = f2bf(v - bf2f(h));
  }
  // ---- copy ff (32 KB), f2 kt0,1 (64 KB) into LDS once ----
  {
    const int4* src = reinterpret_cast<const int4*>(ff);
    int4* dst = reinterpret_cast<int4*>(ffl);
    dst[tid] = src[tid];
    dst[tid + 1024] = src[tid + 1024];
  }
  {
    const int4* src = reinterpret_cast<const int4*>(f2);
    int4* dst = reinterpret_cast<int4*>(f2l);
#pragma unroll
    for (int i = 0; i < 4; ++i) dst[tid + i * 1024] = src[tid + i * 1024];
  }
  // ---- copy w0tf into padded LDS rows (stride W0P dwords, bank-spread) ----
  for (int idx = tid; idx < HID * TDIM; idx += 1024) {
    int n = idx >> 4, c = idx & 15;
    w0l[n * W0P + c] = w0tf[idx];
  }

  const float b0v = b0[nt * 16 + lrow];
  const float b1v = b1[nt * 16 + lrow];
  const float b2v = b2[nt * 16 + lrow];
  const float bfv = (w >= 14) ? bf[(w - 14) * 16 + lrow] : 0.0f;
  __syncthreads();

  // ---- one-time: sacc = state-part of layer0 for this wave's nt ----
  f32x4 sacc = {0.f, 0.f, 0.f, 0.f};
  {
    const unsigned short* aH = &aAh[0][0] + lrow * KPH + quad * 8;
    const unsigned short* aL = &aAl[0][0] + lrow * KPH + quad * 8;
#pragma unroll
    for (int kt = 0; kt < 4; ++kt) {
      short8 ah = *reinterpret_cast<const short8*>(aH + kt * 32);
      short8 al = *reinterpret_cast<const short8*>(aL + kt * 32);
      const unsigned short* p = f0s + (kt * 16 + nt) * 1024 + l * 8;
      short8 bh = *reinterpret_cast<const short8*>(p);
      short8 bl = *reinterpret_cast<const short8*>(p + 512);
      sacc = MFMA(ah, bh, sacc);
      sacc = MFMA(al, bh, sacc);
      sacc = MFMA(ah, bl, sacc);
    }
  }

  // ---- persistent loop-invariant x fragments (kt=0 of layer0, this nt) ----
  short8 Xh, Xl;
  {
    const unsigned short* p = f0x + nt * 1024 + l * 8;
    Xh = *reinterpret_cast<const short8*>(p);
    Xl = *reinterpret_cast<const short8*>(p + 512);
  }

  // ---- F1 slice -> AGPRs (64 dwords), written once, read per iter ----
#define DECL_AG(k) int AH0_##k, AH1_##k, AH2_##k, AH3_##k, \
                       AL0_##k, AL1_##k, AL2_##k, AL3_##k;
  DECL_AG(0) DECL_AG(1) DECL_AG(2) DECL_AG(3)
  DECL_AG(4) DECL_AG(5) DECL_AG(6) DECL_AG(7)
#define LOAD_AG(k) { \
    i32x4 hv = *reinterpret_cast<const i32x4*>(f1 + ((k) * 16 + nt) * 1024 + l * 8); \
    i32x4 lv = *reinterpret_cast<const i32x4*>(f1 + ((k) * 16 + nt) * 1024 + 512 + l * 8); \
    asm volatile("v_accvgpr_write_b32 %0, %1" : "=a"(AH0_##k) : "v"(hv[0])); \
    asm volatile("v_accvgpr_write_b32 %0, %1" : "=a"(AH1_##k) : "v"(hv[1])); \
    asm volatile("v_accvgpr_write_b32 %0, %1" : "=a"(AH2_##k) : "v"(hv[2])); \
    asm volatile("v_accvgpr_write_b32 %0, %1" : "=a"(AH3_##k) : "v"(hv[3])); \
    asm volatile("v_accvgpr_write_b32 %0, %1" : "=a"(AL0_##k) : "v"(lv[0])); \
    asm volatile("v_accvgpr_write_b32 %0, %1" : "=a"(AL1_##k) : "v"(lv[1])); \
    asm volatile("v_accvgpr_write_b32 %0, %1" : "=a"(AL2_##k) : "v"(lv[2])); \
    asm volatile("v_accvgpr_write_b32 %0, %1" : "=a"(AL3_##k) : "v"(lv[3])); }
  LOAD_AG(0) LOAD_AG(1) LOAD_AG(2) LOAD_AG(3)
  LOAD_AG(4) LOAD_AG(5) LOAD_AG(6) LOAD_AG(7)

  // ---- per-lane tf-bias dot (16 f32 FMAs; weights from padded LDS) ----
  float bt;
  auto compute_bt = [&](int tt) {
    const float4* tfr = reinterpret_cast<const float4*>(tf_all + tt * TDIM);
    const float4* wA = reinterpret_cast<const float4*>(&w0l[(nt * 16 + lrow) * W0P]);
    float a = 0.0f;
#pragma unroll
    for (int q = 0; q < 4; ++q) {
      float4 tq = tfr[q];
      float4 wa = wA[q];
      a = fmaf(tq.x, wa.x, a);
      a = fmaf(tq.y, wa.y, a);
      a = fmaf(tq.z, wa.z, a);
      a = fmaf(tq.w, wa.w, a);
    }
    bt = a;
  };
  compute_bt(T_STEPS - 1);

  // epilogue: acc -> mish -> hi(RNE)/lo(trunc) LDS tile (single nt column)
  auto epi_store = [&](const f32x4& acc, float bA,
                       unsigned short* dH, unsigned short* dL) {
#pragma unroll
    for (int reg = 0; reg < 4; ++reg) {
      int orow = quad * 4 + reg;
      float v = mish_f(acc[reg] + bA);
      unsigned short h = f2bf(v);
      dH[orow * KPH + nt * 16 + lrow] = h;
      dL[orow * KPH + nt * 16 + lrow] = f2bf_trunc(v - bf2f(h));
    }
  };

  __syncthreads();  // B0 (full drain, once)

  for (int t = T_STEPS - 1; t >= 0; --t) {
    float sr  = coefs[0 * T_STEPS + t];
    float srm = coefs[1 * T_STEPS + t];
    float c1  = coefs[2 * T_STEPS + t];
    float c2  = coefs[3 * T_STEPS + t];
    float sig = (t != 0) ? coefs[4 * T_STEPS + t] : 0.0f;
    uint32_t k0 = keys[2 * t], k1 = keys[2 * t + 1];

    // ---- L0: x-part only (1 kt), acc starts from persistent state part ----
    {
      f32x4 acc = sacc;
      short8 ah = *reinterpret_cast<const short8*>(&a0h[0][0] + lrow * KPX + quad * 8);
      short8 al = *reinterpret_cast<const short8*>(&a0l[0][0] + lrow * KPX + quad * 8);
      acc = MFMA(ah, Xh, acc);
      acc = MFMA(al, Xh, acc);
      acc = MFMA(ah, Xl, acc);
      epi_store(acc, b0v + bt, &aAh[0][0], &aAl[0][0]);
    }
    barrier_lgkm();  // B1: aA ready (global prefetches stay in flight)

    // ---- L1: weights from AGPRs (zero memory traffic); prefetch F2 kt2 ----
    short8 P2h, P2l;
    {
      f32x4 acc = {0.f, 0.f, 0.f, 0.f};
      const unsigned short* aH = &aAh[0][0] + lrow * KPH + quad * 8;
      const unsigned short* aL = &aAl[0][0] + lrow * KPH + quad * 8;
#define L1_STEP(k) { \
      int h0, h1, h2, h3, lo0, lo1, lo2, lo3; \
      asm volatile("v_accvgpr_read_b32 %0, %1" : "=v"(h0)  : "a"(AH0_##k)); \
      asm volatile("v_accvgpr_read_b32 %0, %1" : "=v"(h1)  : "a"(AH1_##k)); \
      asm volatile("v_accvgpr_read_b32 %0, %1" : "=v"(h2)  : "a"(AH2_##k)); \
      asm volatile("v_accvgpr_read_b32 %0, %1" : "=v"(h3)  : "a"(AH3_##k)); \
      asm volatile("v_accvgpr_read_b32 %0, %1" : "=v"(lo0) : "a"(AL0_##k)); \
      asm volatile("v_accvgpr_read_b32 %0, %1" : "=v"(lo1) : "a"(AL1_##k)); \
      asm volatile("v_accvgpr_read_b32 %0, %1" : "=v"(lo2) : "a"(AL2_##k)); \
      asm volatile("v_accvgpr_read_b32 %0, %1" : "=v"(lo3) : "a"(AL3_##k)); \
      i32x4 hv = {h0, h1, h2, h3}; \
      i32x4 lv = {lo0, lo1, lo2, lo3}; \
      short8 bh = *reinterpret_cast<short8*>(&hv); \
      short8 bl = *reinterpret_cast<short8*>(&lv); \
      short8 ah = *reinterpret_cast<const short8*>(aH + (k) * 32); \
      short8 al = *reinterpret_cast<const short8*>(aL + (k) * 32); \
      acc = MFMA(ah, bh, acc); \
      acc = MFMA(al, bh, acc); \
      acc = MFMA(ah, bl, acc); }
      L1_STEP(0) L1_STEP(1) L1_STEP(2) L1_STEP(3)
      L1_STEP(4) L1_STEP(5) L1_STEP(6) L1_STEP(7)
#undef L1_STEP
      {
        const unsigned short* p = f2 + (2 * 16 + nt) * 1024 + l * 8;
        P2h = *reinterpret_cast<const short8*>(p);
        P2l = *reinterpret_cast<const short8*>(p + 512);
      }
      epi_store(acc, b1v, &aBh[0][0], &aBl[0][0]);
    }
    barrier_lgkm();  // B2: aB ready (P2 still in flight)

    // ---- distributed RNG: threads 0-511, one nzv each (hides in L2 stalls) ----
    if (tid < 512) {
      int d = tid & 31, r = tid >> 5;
      int grow = (r < 8) ? (base + r) : (2048 + base + r - 8);
      uint32_t jflat = (uint32_t)(grow * ADIM + d);
      s_nz[r][d] = bits_to_normal(random_bits32_partitionable(k0, k1, jflat));
    }

    // ---- L2: kt0,1 from LDS; kt2 from prefetch; kt3..7 streamed ----
    {
      f32x4 acc = {0.f, 0.f, 0.f, 0.f};
      const unsigned short* aH = &aBh[0][0] + lrow * KPH + quad * 8;
      const unsigned short* aL = &aBl[0][0] + lrow * KPH + quad * 8;
#pragma unroll
      for (int kt = 0; kt < 2; ++kt) {
        const unsigned short* p = &f2l[0] + (kt * 16 + nt) * 1024 + l * 8;
        short8 bh = *reinterpret_cast<const short8*>(p);
        short8 bl = *reinterpret_cast<const short8*>(p + 512);
        short8 ah = *reinterpret_cast<const short8*>(aH + kt * 32);
        short8 al = *reinterpret_cast<const short8*>(aL + kt * 32);
        acc = MFMA(ah, bh, acc);
        acc = MFMA(al, bh, acc);
        acc = MFMA(ah, bl, acc);
      }
      {  // kt = 2 from prefetch
        short8 ah = *reinterpret_cast<const short8*>(aH + 2 * 32);
        short8 al = *reinterpret_cast<const short8*>(aL + 2 * 32);
        acc = MFMA(ah, P2h, acc);
        acc = MFMA(al, P2h, acc);
        acc = MFMA(ah, P2l, acc);
      }
#pragma unroll
      for (int kt = 3; kt < 8; ++kt) {
        const unsigned short* p = f2 + (kt * 16 + nt) * 1024 + l * 8;
        short8 bh = *reinterpret_cast<const short8*>(p);
        short8 bl = *reinterpret_cast<const short8*>(p + 512);
        short8 ah = *reinterpret_cast<const short8*>(aH + kt * 32);
        short8 al = *reinterpret_cast<const short8*>(aL + kt * 32);
        acc = MFMA(ah, bh, acc);
        acc = MFMA(al, bh, acc);
        acc = MFMA(ah, bl, acc);
      }
      epi_store(acc, b2v, &aAh[0][0], &aAl[0][0]);
    }
    barrier_lgkm();  // B3: aA(L2 out) + s_nz ready

    // ---- LF + fused posterior on waves 14,15 (eps stays in registers) ----
    if (w >= 14) {
      f32x4 acc = {0.f, 0.f, 0.f, 0.f};
      const unsigned short* aH = &aAh[0][0] + lrow * KPH + quad * 8;
      const unsigned short* aL = &aAl[0][0] + lrow * KPH + quad * 8;
      const int wf2 = w - 14;
#pragma unroll
      for (int kt = 0; kt < 8; ++kt) {
        const unsigned short* p = &ffl[0] + (kt * 2 + wf2) * 1024 + l * 8;
        short8 bh = *reinterpret_cast<const short8*>(p);
        short8 bl = *reinterpret_cast<const short8*>(p + 512);
        short8 ah = *reinterpret_cast<const short8*>(aH + kt * 32);
        short8 al = *reinterpret_cast<const short8*>(aL + kt * 32);
        acc = MFMA(ah, bh, acc);
        acc = MFMA(al, bh, acc);
        acc = MFMA(ah, bl, acc);
      }
      const int d = wf2 * 16 + lrow;
#pragma unroll
      for (int reg = 0; reg < 4; ++reg) {
        int r = quad * 4 + reg;
        float eps = acc[reg] + bfv;
        float nzv = s_nz[r][d];
        float xv = s_x[r][d];
        float x0v = fminf(fmaxf(sr * xv - srm * eps, -1.0f), 1.0f);
        float xn = c1 * x0v + c2 * xv + sig * nzv;
        s_x[r][d] = xn;
        unsigned short h = f2bf(xn);
        a0h[r][d] = h; a0l[r][d] = f2bf_trunc(xn - bf2f(h));
      }
    }
    // next iteration's tf-bias (all waves; overlaps LF+posterior)
    compute_bt((t > 0) ? (t - 1) : 0);
    barrier_lgkm();  // B4: a0/s_x ready for next L0
  }

  // ---- output ----
  if (tid < 512) {
    int r = tid >> 5, d = tid & 31;
    int grow = (r < 8) ? (base + r) : (2048 + base + r - 8);
    out[grow * ADIM + d] = fminf(fmaxf(s_x[r][d], -1.0f), 1.0f);
  }
}

// ---------------- launcher ----------------
extern "C" void kernel_launch(void* const* d_in, const int* in_sizes, int n_in,
                              void* d_out, int out_size, void* d_ws, size_t ws_size,
                              hipStream_t stream) {
  const float* state = (const float*)d_in[0];
  const float* x_init = (const float*)d_in[1];
  const float* w_t1 = (const float*)d_in[2];
  const float* b_t1 = (const float*)d_in[3];
  const float* w_t2 = (const float*)d_in[4];
  const float* b_t2 = (const float*)d_in[5];
  const float* w0 = (const float*)d_in[6];
  const float* b0 = (const float*)d_in[7];
  const float* w1 = (const float*)d_in[8];
  const float* b1 = (const float*)d_in[9];
  const float* w2 = (const float*)d_in[10];
  const float* b2 = (const float*)d_in[11];
  const float* wf = (const float*)d_in[12];
  const float* bf = (const float*)d_in[13];
  float* out = (float*)d_out;

  // ws layout (f32 units unless noted), total ~829 KB:
  //   tf_all[16000] | w0tf[4096] | coefs[5000] | keys[2000] u32
  //   | f0x[16K ush] | f0s[64K] | f1[128K] | f2[128K] | ff[16K]
  float* tf_all = (float*)d_ws;
  float* w0tf = tf_all + T_STEPS * TDIM;
  float* coefs = w0tf + HID * TDIM;
  uint32_t* keys = (uint32_t*)(coefs + 5 * T_STEPS);
  unsigned short* f0x = (unsigned short*)(keys + 2 * T_STEPS);
  unsigned short* f0s = f0x + 16 * 1024;
  unsigned short* f1 = f0s + 64 * 1024;
  unsigned short* f2 = f1 + 128 * 1024;
  unsigned short* ff = f2 + 128 * 1024;

  precompute_kernel<<<T_STEPS, 64, 0, stream>>>(w_t1, b_t1, w_t2, b_t2,
                                                tf_all, coefs, keys);
  prep_frags<<<356, 64, 0, stream>>>(w0, w1, w2, wf, f0x, f0s, f1, f2, ff, w0tf);
  diffusion_main<<<256, 1024, 0, stream>>>(state, x_init, b0, b1, b2, bf,
                                           f0x, f0s, f1, f2, ff,
                                           tf_all, w0tf, coefs, keys, out);
}

// Round 18
// 6495.685 us; speedup vs baseline: 3.1632x; 1.0335x over previous
//
#include <hip/hip_runtime.h>
#include <stdint.h>

// ---------------- constants ----------------
#define T_STEPS 1000
#define SDIM    128
#define ADIM    32
#define HID     256
#define TDIM    16
#define KPX     40                     // padded K stride for x tile (32 used)
#define KPH     264                    // padded K stride for hidden tiles (256 used)
                                       // NOTE: must stay ≡ 0 mod 8 ushorts (16B) so
                                       // ds_read_b128 alignment holds (KPH=268 broke
                                       // this: b128 reads split, 2x slowdown, r13)
#define W0P     20                     // padded row stride (dwords) for w0l in LDS

typedef __attribute__((ext_vector_type(8))) short short8;   // 8 bf16 (4 VGPRs)
typedef __attribute__((ext_vector_type(4))) float f32x4;    // MFMA accumulator
typedef __attribute__((ext_vector_type(4))) int   i32x4;

#define MFMA(A, B, C) __builtin_amdgcn_mfma_f32_16x16x32_bf16((A), (B), (C), 0, 0, 0)

// Barrier that drains LDS ops but leaves global loads (prefetches) in flight.
__device__ __forceinline__ void barrier_lgkm() {
  asm volatile("s_waitcnt lgkmcnt(0)" ::: "memory");
  __builtin_amdgcn_s_barrier();
  asm volatile("" ::: "memory");
}

// ---------------- bf16 helpers ----------------
// RNE (used for hi plane / staging)
__device__ __forceinline__ unsigned short f2bf(float f) {
  uint32_t u = __float_as_uint(f);
  u = u + 0x7FFFu + ((u >> 16) & 1u);
  return (unsigned short)(u >> 16);
}
__device__ __forceinline__ float bf2f(unsigned short h) {
  return __uint_as_float(((uint32_t)h) << 16);
}
// Truncating convert for the LO plane only (residual ≤ 2^-9|v|; trunc-vs-RNE
// differs ≤ 2^-17|v|, same order as the split scheme's inherent error). r16
__device__ __forceinline__ unsigned short f2bf_trunc(float f) {
  return (unsigned short)(__float_as_uint(f) >> 16);
}

// ---------------- threefry2x32 (exact JAX semantics) ----------------
__device__ __forceinline__ uint32_t rotl32(uint32_t v, int d) {
  return (v << d) | (v >> (32 - d));
}
__device__ __forceinline__ void threefry2x32(uint32_t k0, uint32_t k1,
                                             uint32_t x0, uint32_t x1,
                                             uint32_t& o0, uint32_t& o1) {
  uint32_t ks0 = k0, ks1 = k1, ks2 = k0 ^ k1 ^ 0x1BD11BDAu;
  x0 += ks0; x1 += ks1;
#define TF_ROUND(r) { x0 += x1; x1 = rotl32(x1, (r)); x1 ^= x0; }
  TF_ROUND(13) TF_ROUND(15) TF_ROUND(26) TF_ROUND(6)
  x0 += ks1; x1 += ks2 + 1u;
  TF_ROUND(17) TF_ROUND(29) TF_ROUND(16) TF_ROUND(24)
  x0 += ks2; x1 += ks0 + 2u;
  TF_ROUND(13) TF_ROUND(15) TF_ROUND(26) TF_ROUND(6)
  x0 += ks0; x1 += ks1 + 3u;
  TF_ROUND(17) TF_ROUND(29) TF_ROUND(16) TF_ROUND(24)
  x0 += ks1; x1 += ks2 + 4u;
  TF_ROUND(13) TF_ROUND(15) TF_ROUND(26) TF_ROUND(6)
  x0 += ks2; x1 += ks0 + 5u;
#undef TF_ROUND
  o0 = x0; o1 = x1;
}
__device__ __forceinline__ uint32_t random_bits32_partitionable(uint32_t k0, uint32_t k1,
                                                               uint32_t j) {
  uint32_t o0, o1;
  threefry2x32(k0, k1, 0u, j, o0, o1);
  return o0 ^ o1;
}

// ---------------- XLA ErfInv (f32 Giles polynomial), fast-log variant ----------
// w = -log(1-x^2): fmaf(x,-x,1) has ONE rounding (no cancellation), v_log ~1ulp.
// nzv perturbation ≲1e-6 absolute — 2 orders below the bf16 error floor. (r16)
__device__ __forceinline__ float erfinv_f32(float x) {
  float w = -__logf(fmaf(x, -x, 1.0f));
  float p;
  if (w < 5.0f) {
    w = w - 2.5f;
    p = 2.81022636e-08f;
    p = fmaf(p, w, 3.43273939e-07f);
    p = fmaf(p, w, -3.5233877e-06f);
    p = fmaf(p, w, -4.39150654e-06f);
    p = fmaf(p, w, 0.00021858087f);
    p = fmaf(p, w, -0.00125372503f);
    p = fmaf(p, w, -0.00417768164f);
    p = fmaf(p, w, 0.246640727f);
    p = fmaf(p, w, 1.50140941f);
  } else {
    w = sqrtf(w) - 3.0f;
    p = -0.000200214257f;
    p = fmaf(p, w, 0.000100950558f);
    p = fmaf(p, w, 0.00134934322f);
    p = fmaf(p, w, -0.00367342844f);
    p = fmaf(p, w, 0.00573950773f);
    p = fmaf(p, w, -0.0076224613f);
    p = fmaf(p, w, 0.00943887047f);
    p = fmaf(p, w, 1.00167406f);
    p = fmaf(p, w, 2.83297682f);
  }
  return p * x;
}
__device__ __forceinline__ float bits_to_normal(uint32_t bits) {
  float f = __uint_as_float((bits >> 9) | 0x3F800000u) - 1.0f;   // [0,1)
  float u = f * 2.0f + (-0.99999994f);
  u = fmaxf(-0.99999994f, u);
  return 1.41421356237309515f * erfinv_f32(u);   // sqrt(2) as f32
}

// mish(x) = x * t/(t+2), t = e^x (e^x + 2)
// FAST variant: v_exp_f32 (~2ulp) + v_rcp_f32 (~1ulp). (r15, verified)
__device__ __forceinline__ float mish_f(float x) {
  float e = __expf(fminf(x, 20.0f));
  float t = fmaf(e, e, 2.0f * e);
  return x * t * __builtin_amdgcn_rcpf(t + 2.0f);
}

// ---------------- precompute: tf_all[1000][16], coefs[5][1000], keys[1000][2] -----
__global__ __launch_bounds__(64)
void precompute_kernel(const float* __restrict__ w_t1, const float* __restrict__ b_t1,
                       const float* __restrict__ w_t2, const float* __restrict__ b_t2,
                       float* __restrict__ tf_all, float* __restrict__ coefs,
                       uint32_t* __restrict__ keys) {
  const int i = blockIdx.x;
  const int j = threadIdx.x;
  const float tv = (float)i;
  __shared__ float hid[32];
  const float CF = (float)(-1.3157629102823120);  // -log(10000)/7
  if (j < 32) {
    float acc = b_t1[j];
#pragma unroll
    for (int k = 0; k < 16; ++k) {
      int kf = (k < 8) ? k : (k - 8);
      float fr = expf((float)kf * CF);
      float ang = tv * fr;
      float te = (k < 8) ? sinf(ang) : cosf(ang);
      acc = fmaf(te, w_t1[k * 32 + j], acc);
    }
    float e = __expf(fminf(acc, 20.0f));
    float t = fmaf(e, e, 2.0f * e);
    hid[j] = acc * t * __builtin_amdgcn_rcpf(t + 2.0f);
  }
  __syncthreads();
  if (j < 16) {
    float acc = b_t2[j];
#pragma unroll
    for (int k2 = 0; k2 < 32; ++k2) acc = fmaf(hid[k2], w_t2[k2 * 16 + j], acc);
    tf_all[i * TDIM + j] = acc;
  }
  if (j == 0) {
    double t = (double)(i + 1);
    double ac  = exp(-0.1 * t / 1000.0 - 4.95 * t * t / 1.0e6);
    double acp = (i == 0) ? 1.0
        : exp(-0.1 * (t - 1.0) / 1000.0 - 4.95 * (t - 1.0) * (t - 1.0) / 1.0e6);
    double alpha = exp(-0.1 / 1000.0 - 4.95 * (2.0 * t - 1.0) / 1.0e6);
    double beta = 1.0 - alpha;
    double sr   = sqrt(1.0 / ac);
    double srm1 = sqrt(1.0 / ac - 1.0);
    double c1 = beta * sqrt(acp) / (1.0 - ac);
    double c2 = (1.0 - acp) * sqrt(alpha) / (1.0 - ac);
    double pv = beta * (1.0 - acp) / (1.0 - ac);
    double lv = log(fmax(pv, 1.0e-20));
    coefs[0 * T_STEPS + i] = (float)sr;
    coefs[1 * T_STEPS + i] = (float)srm1;
    coefs[2 * T_STEPS + i] = (float)c1;
    coefs[3 * T_STEPS + i] = (float)c2;
    float lvf = (float)lv;
    coefs[4 * T_STEPS + i] = expf(0.5f * lvf);
    uint32_t o0, o1;
    threefry2x32(0u, 1u, 0u, (uint32_t)i, o0, o1);
    keys[2 * i]     = o0;
    keys[2 * i + 1] = o1;
  }
}

// -------- prep: MFMA B-fragment hi/lo layout + w0tf transpose ---------------------
__global__ __launch_bounds__(64)
void prep_frags(const float* __restrict__ w0, const float* __restrict__ w1,
                const float* __restrict__ w2, const float* __restrict__ wf,
                unsigned short* __restrict__ f0x, unsigned short* __restrict__ f0s,
                unsigned short* __restrict__ f1, unsigned short* __restrict__ f2,
                unsigned short* __restrict__ ff, float* __restrict__ w0tf) {
  const int bid = blockIdx.x;   // 0..355
  const int l = threadIdx.x;    // 0..63
  if (bid >= 352) {             // w0tf transpose
    int n = (bid - 352) * 64 + l;
#pragma unroll
    for (int c = 0; c < 16; ++c) w0tf[n * 16 + c] = w0[(32 + c) * HID + n];
    return;
  }
  const float* W; unsigned short* F; int NT, N, idx, rowoff, Kmax;
  if (bid < 16)       { W = w0; F = f0x; NT = 16; N = 256; idx = bid;       rowoff = 0;  Kmax = 32;  }
  else if (bid < 80)  { W = w0; F = f0s; NT = 16; N = 256; idx = bid - 16;  rowoff = 48; Kmax = 128; }
  else if (bid < 208) { W = w1; F = f1;  NT = 16; N = 256; idx = bid - 80;  rowoff = 0;  Kmax = 256; }
  else if (bid < 336) { W = w2; F = f2;  NT = 16; N = 256; idx = bid - 208; rowoff = 0;  Kmax = 256; }
  else                { W = wf; F = ff;  NT = 2;  N = 32;  idx = bid - 336; rowoff = 0;  Kmax = 256; }
  const int kt = idx / NT, nt = idx % NT;
  const int n = nt * 16 + (l & 15);
  const int kbase = kt * 32 + (l >> 4) * 8;
  unsigned short* dst = F + idx * 1024 + l * 8;
#pragma unroll
  for (int j = 0; j < 8; ++j) {
    int k = kbase + j;
    float v = (k < Kmax) ? W[(rowoff + k) * N + n] : 0.0f;
    unsigned short h = f2bf(v);
    dst[j]       = h;
    dst[512 + j] = f2bf(v - bf2f(h));   // weights converted once: keep RNE
  }
}

// ---------------- persistent main kernel ------------------------------------------
// Grid 256 (1 block/CU), 1024 threads (16 waves), wave w owns nt-column w.
// LDS-resident: ff (32K), w0tf padded (20K), f2 kt0-1 (64K). F1 in AGPRs via
// v_accvgpr_write/read (compiler-managed MFMA hazards; r17's direct-AGPR asm
// MFMA corrupted results — hazard nops are compiler-inserted only for intrinsics).
// Barriers drain lgkmcnt only; RNG distributed; LF+posterior fused. 4 barriers/iter.
// Fast mish (r15) + fast log / truncated lo-plane (r16).
__global__ __launch_bounds__(1024)
void diffusion_main(const float* __restrict__ state, const float* __restrict__ x_init,
                    const float* __restrict__ b0, const float* __restrict__ b1,
                    const float* __restrict__ b2, const float* __restrict__ bf,
                    const unsigned short* __restrict__ f0x, const unsigned short* __restrict__ f0s,
                    const unsigned short* __restrict__ f1, const unsigned short* __restrict__ f2,
                    const unsigned short* __restrict__ ff,
                    const float* __restrict__ tf_all, const float* __restrict__ w0tf,
                    const float* __restrict__ coefs,
                    const uint32_t* __restrict__ keys, float* __restrict__ out) {
  __shared__ __align__(16) unsigned short a0h[16][KPX], a0l[16][KPX];
  __shared__ __align__(16) unsigned short aAh[16][KPH], aAl[16][KPH];
  __shared__ __align__(16) unsigned short aBh[16][KPH], aBl[16][KPH];
  __shared__ __align__(16) unsigned short ffl[16 * 1024];   // ff resident (32 KB)
  __shared__ __align__(16) unsigned short f2l[32 * 1024];   // f2 kt0,1 resident (64 KB)
  __shared__ __align__(16) float w0l[HID * W0P];            // w0tf resident, padded (20 KB)
  __shared__ float s_x[16][ADIM];
  __shared__ float s_nz[16][33];                            // distributed RNG output

  const int tid = threadIdx.x;          // 0..1023
  const int base = blockIdx.x * 8;
  const int l = tid & 63;               // lane
  const int w = tid >> 6;               // wave 0..15
  const int lrow = l & 15;
  const int quad = l >> 4;              // 0..3
  const int nt = w;                     // one col-tile per wave

  // ---- stage x_init (16x32 = 512 elems; tid<512) ----
  if (tid < 512) {
    int r = tid >> 5, d = tid & 31;
    int grow = (r < 8) ? (base + r) : (2048 + base + r - 8);
    float v = x_init[grow * ADIM + d];
    s_x[r][d] = v;
    unsigned short h = f2bf(v);
    a0h[r][d] = h; a0l[r][d] = f2bf(v - bf2f(h));
  }
  // ---- stage state into aA cols 0..127 (one-time) ----
  for (int idx = tid; idx < 16 * SDIM; idx += 1024) {
    int r = idx >> 7, c = idx & 127;
    int grow = (r < 8) ? (base + r) : (2048 + base + r - 8);
    float v = state[grow * SDIM + c];
    unsigned short h = f2bf(v);
    aAh[r][c] = h; aAl[r][c] = f2bf(v - bf2f(h));
  }
  // ---- copy ff (32 KB), f2 kt0,1 (64 KB) into LDS once ----
  {
    const int4* src = reinterpret_cast<const int4*>(ff);
    int4* dst = reinterpret_cast<int4*>(ffl);
    dst[tid] = src[tid];
    dst[tid + 1024] = src[tid + 1024];
  }
  {
    const int4* src = reinterpret_cast<const int4*>(f2);
    int4* dst = reinterpret_cast<int4*>(f2l);
#pragma unroll
    for (int i = 0; i < 4; ++i) dst[tid + i * 1024] = src[tid + i * 1024];
  }
  // ---- copy w0tf into padded LDS rows (stride W0P dwords, bank-spread) ----
  for (int idx = tid; idx < HID * TDIM; idx += 1024) {
    int n = idx >> 4, c = idx & 15;
    w0l[n * W0P + c] = w0tf[idx];
  }

  const float b0v = b0[nt * 16 + lrow];
  const float b1v = b1[nt * 16 + lrow];
  const float b2v = b2[nt * 16 + lrow];
  const float bfv = (w >= 14) ? bf[(w - 14) * 16 + lrow] : 0.0f;
  __syncthreads();

  // ---- one-time: sacc = state-part of layer0 for this wave's nt ----
  f32x4 sacc = {0.f, 0.f, 0.f, 0.f};
  {
    const unsigned short* aH = &aAh[0][0] + lrow * KPH + quad * 8;
    const unsigned short* aL = &aAl[0][0] + lrow * KPH + quad * 8;
#pragma unroll
    for (int kt = 0; kt < 4; ++kt) {
      short8 ah = *reinterpret_cast<const short8*>(aH + kt * 32);
      short8 al = *reinterpret_cast<const short8*>(aL + kt * 32);
      const unsigned short* p = f0s + (kt * 16 + nt) * 1024 + l * 8;
      short8 bh = *reinterpret_cast<const short8*>(p);
      short8 bl = *reinterpret_cast<const short8*>(p + 512);
      sacc = MFMA(ah, bh, sacc);
      sacc = MFMA(al, bh, sacc);
      sacc = MFMA(ah, bl, sacc);
    }
  }

  // ---- persistent loop-invariant x fragments (kt=0 of layer0, this nt) ----
  short8 Xh, Xl;
  {
    const unsigned short* p = f0x + nt * 1024 + l * 8;
    Xh = *reinterpret_cast<const short8*>(p);
    Xl = *reinterpret_cast<const short8*>(p + 512);
  }

  // ---- F1 slice -> AGPRs (64 dwords), written once, read per iter ----
#define DECL_AG(k) int AH0_##k, AH1_##k, AH2_##k, AH3_##k, \
                       AL0_##k, AL1_##k, AL2_##k, AL3_##k;
  DECL_AG(0) DECL_AG(1) DECL_AG(2) DECL_AG(3)
  DECL_AG(4) DECL_AG(5) DECL_AG(6) DECL_AG(7)
#define LOAD_AG(k) { \
    i32x4 hv = *reinterpret_cast<const i32x4*>(f1 + ((k) * 16 + nt) * 1024 + l * 8); \
    i32x4 lv = *reinterpret_cast<const i32x4*>(f1 + ((k) * 16 + nt) * 1024 + 512 + l * 8); \
    asm volatile("v_accvgpr_write_b32 %0, %1" : "=a"(AH0_##k) : "v"(hv[0])); \
    asm volatile("v_accvgpr_write_b32 %0, %1" : "=a"(AH1_##k) : "v"(hv[1])); \
    asm volatile("v_accvgpr_write_b32 %0, %1" : "=a"(AH2_##k) : "v"(hv[2])); \
    asm volatile("v_accvgpr_write_b32 %0, %1" : "=a"(AH3_##k) : "v"(hv[3])); \
    asm volatile("v_accvgpr_write_b32 %0, %1" : "=a"(AL0_##k) : "v"(lv[0])); \
    asm volatile("v_accvgpr_write_b32 %0, %1" : "=a"(AL1_##k) : "v"(lv[1])); \
    asm volatile("v_accvgpr_write_b32 %0, %1" : "=a"(AL2_##k) : "v"(lv[2])); \
    asm volatile("v_accvgpr_write_b32 %0, %1" : "=a"(AL3_##k) : "v"(lv[3])); }
  LOAD_AG(0) LOAD_AG(1) LOAD_AG(2) LOAD_AG(3)
  LOAD_AG(4) LOAD_AG(5) LOAD_AG(6) LOAD_AG(7)

  // ---- per-lane tf-bias dot (16 f32 FMAs; weights from padded LDS) ----
  float bt;
  auto compute_bt = [&](int tt) {
    const float4* tfr = reinterpret_cast<const float4*>(tf_all + tt * TDIM);
    const float4* wA = reinterpret_cast<const float4*>(&w0l[(nt * 16 + lrow) * W0P]);
    float a = 0.0f;
#pragma unroll
    for (int q = 0; q < 4; ++q) {
      float4 tq = tfr[q];
      float4 wa = wA[q];
      a = fmaf(tq.x, wa.x, a);
      a = fmaf(tq.y, wa.y, a);
      a = fmaf(tq.z, wa.z, a);
      a = fmaf(tq.w, wa.w, a);
    }
    bt = a;
  };
  compute_bt(T_STEPS - 1);

  // epilogue: acc -> mish -> hi(RNE)/lo(trunc) LDS tile (single nt column)
  auto epi_store = [&](const f32x4& acc, float bA,
                       unsigned short* dH, unsigned short* dL) {
#pragma unroll
    for (int reg = 0; reg < 4; ++reg) {
      int orow = quad * 4 + reg;
      float v = mish_f(acc[reg] + bA);
      unsigned short h = f2bf(v);
      dH[orow * KPH + nt * 16 + lrow] = h;
      dL[orow * KPH + nt * 16 + lrow] = f2bf_trunc(v - bf2f(h));
    }
  };

  __syncthreads();  // B0 (full drain, once)

  for (int t = T_STEPS - 1; t >= 0; --t) {
    float sr  = coefs[0 * T_STEPS + t];
    float srm = coefs[1 * T_STEPS + t];
    float c1  = coefs[2 * T_STEPS + t];
    float c2  = coefs[3 * T_STEPS + t];
    float sig = (t != 0) ? coefs[4 * T_STEPS + t] : 0.0f;
    uint32_t k0 = keys[2 * t], k1 = keys[2 * t + 1];

    // ---- L0: x-part only (1 kt), acc starts from persistent state part ----
    {
      f32x4 acc = sacc;
      short8 ah = *reinterpret_cast<const short8*>(&a0h[0][0] + lrow * KPX + quad * 8);
      short8 al = *reinterpret_cast<const short8*>(&a0l[0][0] + lrow * KPX + quad * 8);
      acc = MFMA(ah, Xh, acc);
      acc = MFMA(al, Xh, acc);
      acc = MFMA(ah, Xl, acc);
      epi_store(acc, b0v + bt, &aAh[0][0], &aAl[0][0]);
    }
    barrier_lgkm();  // B1: aA ready (global prefetches stay in flight)

    // ---- L1: weights from AGPRs (zero memory traffic); prefetch F2 kt2 ----
    short8 P2h, P2l;
    {
      f32x4 acc = {0.f, 0.f, 0.f, 0.f};
      const unsigned short* aH = &aAh[0][0] + lrow * KPH + quad * 8;
      const unsigned short* aL = &aAl[0][0] + lrow * KPH + quad * 8;
#define L1_STEP(k) { \
      int h0, h1, h2, h3, lo0, lo1, lo2, lo3; \
      asm volatile("v_accvgpr_read_b32 %0, %1" : "=v"(h0)  : "a"(AH0_##k)); \
      asm volatile("v_accvgpr_read_b32 %0, %1" : "=v"(h1)  : "a"(AH1_##k)); \
      asm volatile("v_accvgpr_read_b32 %0, %1" : "=v"(h2)  : "a"(AH2_##k)); \
      asm volatile("v_accvgpr_read_b32 %0, %1" : "=v"(h3)  : "a"(AH3_##k)); \
      asm volatile("v_accvgpr_read_b32 %0, %1" : "=v"(lo0) : "a"(AL0_##k)); \
      asm volatile("v_accvgpr_read_b32 %0, %1" : "=v"(lo1) : "a"(AL1_##k)); \
      asm volatile("v_accvgpr_read_b32 %0, %1" : "=v"(lo2) : "a"(AL2_##k)); \
      asm volatile("v_accvgpr_read_b32 %0, %1" : "=v"(lo3) : "a"(AL3_##k)); \
      i32x4 hv = {h0, h1, h2, h3}; \
      i32x4 lv = {lo0, lo1, lo2, lo3}; \
      short8 bh = *reinterpret_cast<short8*>(&hv); \
      short8 bl = *reinterpret_cast<short8*>(&lv); \
      short8 ah = *reinterpret_cast<const short8*>(aH + (k) * 32); \
      short8 al = *reinterpret_cast<const short8*>(aL + (k) * 32); \
      acc = MFMA(ah, bh, acc); \
      acc = MFMA(al, bh, acc); \
      acc = MFMA(ah, bl, acc); }
      L1_STEP(0) L1_STEP(1) L1_STEP(2) L1_STEP(3)
      L1_STEP(4) L1_STEP(5) L1_STEP(6) L1_STEP(7)
#undef L1_STEP
      {
        const unsigned short* p = f2 + (2 * 16 + nt) * 1024 + l * 8;
        P2h = *reinterpret_cast<const short8*>(p);
        P2l = *reinterpret_cast<const short8*>(p + 512);
      }
      epi_store(acc, b1v, &aBh[0][0], &aBl[0][0]);
    }
    barrier_lgkm();  // B2: aB ready (P2 still in flight)

    // ---- distributed RNG: threads 0-511, one nzv each (hides in L2 stalls) ----
    if (tid < 512) {
      int d = tid & 31, r = tid >> 5;
      int grow = (r < 8) ? (base + r) : (2048 + base + r - 8);
      uint32_t jflat = (uint32_t)(grow * ADIM + d);
      s_nz[r][d] = bits_to_normal(random_bits32_partitionable(k0, k1, jflat));
    }

    // ---- L2: kt0,1 from LDS; kt2 from prefetch; kt3..7 streamed ----
    {
      f32x4 acc = {0.f, 0.f, 0.f, 0.f};
      const unsigned short* aH = &aBh[0][0] + lrow * KPH + quad * 8;
      const unsigned short* aL = &aBl[0][0] + lrow * KPH + quad * 8;
#pragma unroll
      for (int kt = 0; kt < 2; ++kt) {
        const unsigned short* p = &f2l[0] + (kt * 16 + nt) * 1024 + l * 8;
        short8 bh = *reinterpret_cast<const short8*>(p);
        short8 bl = *reinterpret_cast<const short8*>(p + 512);
        short8 ah = *reinterpret_cast<const short8*>(aH + kt * 32);
        short8 al = *reinterpret_cast<const short8*>(aL + kt * 32);
        acc = MFMA(ah, bh, acc);
        acc = MFMA(al, bh, acc);
        acc = MFMA(ah, bl, acc);
      }
      {  // kt = 2 from prefetch
        short8 ah = *reinterpret_cast<const short8*>(aH + 2 * 32);
        short8 al = *reinterpret_cast<const short8*>(aL + 2 * 32);
        acc = MFMA(ah, P2h, acc);
        acc = MFMA(al, P2h, acc);
        acc = MFMA(ah, P2l, acc);
      }
#pragma unroll
      for (int kt = 3; kt < 8; ++kt) {
        const unsigned short* p = f2 + (kt * 16 + nt) * 1024 + l * 8;
        short8 bh = *reinterpret_cast<const short8*>(p);
        short8 bl = *reinterpret_cast<const short8*>(p + 512);
        short8 ah = *reinterpret_cast<const short8*>(aH + kt * 32);
        short8 al = *reinterpret_cast<const short8*>(aL + kt * 32);
        acc = MFMA(ah, bh, acc);
        acc = MFMA(al, bh, acc);
        acc = MFMA(ah, bl, acc);
      }
      epi_store(acc, b2v, &aAh[0][0], &aAl[0][0]);
    }
    barrier_lgkm();  // B3: aA(L2 out) + s_nz ready

    // ---- LF + fused posterior on waves 14,15 (eps stays in registers) ----
    if (w >= 14) {
      f32x4 acc = {0.f, 0.f, 0.f, 0.f};
      const unsigned short* aH = &aAh[0][0] + lrow * KPH + quad * 8;
      const unsigned short* aL = &aAl[0][0] + lrow * KPH + quad * 8;
      const int wf2 = w - 14;
#pragma unroll
      for (int kt = 0; kt < 8; ++kt) {
        const unsigned short* p = &ffl[0] + (kt * 2 + wf2) * 1024 + l * 8;
        short8 bh = *reinterpret_cast<const short8*>(p);
        short8 bl = *reinterpret_cast<const short8*>(p + 512);
        short8 ah = *reinterpret_cast<const short8*>(aH + kt * 32);
        short8 al = *reinterpret_cast<const short8*>(aL + kt * 32);
        acc = MFMA(ah, bh, acc);
        acc = MFMA(al, bh, acc);
        acc = MFMA(ah, bl, acc);
      }
      const int d = wf2 * 16 + lrow;
#pragma unroll
      for (int reg = 0; reg < 4; ++reg) {
        int r = quad * 4 + reg;
        float eps = acc[reg] + bfv;
        float nzv = s_nz[r][d];
        float xv = s_x[r][d];
        float x0v = fminf(fmaxf(sr * xv - srm * eps, -1.0f), 1.0f);
        float xn = c1 * x0v + c2 * xv + sig * nzv;
        s_x[r][d] = xn;
        unsigned short h = f2bf(xn);
        a0h[r][d] = h; a0l[r][d] = f2bf_trunc(xn - bf2f(h));
      }
    }
    // next iteration's tf-bias (all waves; overlaps LF+posterior)
    compute_bt((t > 0) ? (t - 1) : 0);
    barrier_lgkm();  // B4: a0/s_x ready for next L0
  }

  // ---- output ----
  if (tid < 512) {
    int r = tid >> 5, d = tid & 31;
    int grow = (r < 8) ? (base + r) : (2048 + base + r - 8);
    out[grow * ADIM + d] = fminf(fmaxf(s_x[r][d], -1.0f), 1.0f);
  }
}

// ---------------- launcher ----------------
extern "C" void kernel_launch(void* const* d_in, const int* in_sizes, int n_in,
                              void* d_out, int out_size, void* d_ws, size_t ws_size,
                              hipStream_t stream) {
  const float* state = (const float*)d_in[0];
  const float* x_init = (const float*)d_in[1];
  const float* w_t1 = (const float*)d_in[2];
  const float* b_t1 = (const float*)d_in[3];
  const float* w_t2 = (const float*)d_in[4];
  const float* b_t2 = (const float*)d_in[5];
  const float* w0 = (const float*)d_in[6];
  const float* b0 = (const float*)d_in[7];
  const float* w1 = (const float*)d_in[8];
  const float* b1 = (const float*)d_in[9];
  const float* w2 = (const float*)d_in[10];
  const float* b2 = (const float*)d_in[11];
  const float* wf = (const float*)d_in[12];
  const float* bf = (const float*)d_in[13];
  float* out = (float*)d_out;

  // ws layout (f32 units unless noted), total ~829 KB:
  //   tf_all[16000] | w0tf[4096] | coefs[5000] | keys[2000] u32
  //   | f0x[16K ush] | f0s[64K] | f1[128K] | f2[128K] | ff[16K]
  float* tf_all = (float*)d_ws;
  float* w0tf = tf_all + T_STEPS * TDIM;
  float* coefs = w0tf + HID * TDIM;
  uint32_t* keys = (uint32_t*)(coefs + 5 * T_STEPS);
  unsigned short* f0x = (unsigned short*)(keys + 2 * T_STEPS);
  unsigned short* f0s = f0x + 16 * 1024;
  unsigned short* f1 = f0s + 64 * 1024;
  unsigned short* f2 = f1 + 128 * 1024;
  unsigned short* ff = f2 + 128 * 1024;

  precompute_kernel<<<T_STEPS, 64, 0, stream>>>(w_t1, b_t1, w_t2, b_t2,
                                                tf_all, coefs, keys);
  prep_frags<<<356, 64, 0, stream>>>(w0, w1, w2, wf, f0x, f0s, f1, f2, ff, w0tf);
  diffusion_main<<<256, 1024, 0, stream>>>(state, x_init, b0, b1, b2, bf,
                                           f0x, f0s, f1, f2, ff,
                                           tf_all, w0tf, coefs, keys, out);
}